// Round 6
// baseline (5618.942 us; speedup 1.0000x reference)
//
#include <hip/hip_runtime.h>
#include <cstdint>
#include <cstddef>

// Rank1BayesianRNN on MI355X — round 6: 8-wave persistent kernel, fence-free.
// vs round 5 (20.6us/step, MfmaUtil 8.4%, Occ 12.4%):
//  * 512 thr/WG (2 waves/SIMD): waves 0-3 k<512 + cell, waves 4-7 k>=512
//    -> 16KB LDS partial reduce. TLP doubles, per-wave work halves.
//  * NO per-step acquire fence: h exchange via sc1 (agent RELAXED) atomics
//    only; barrier arrive is RELEASE. L2 stays warm for seq.
//  * barrier: 8 sub-counters x 8 arrivers per rb-group (was 64 RMWs on one).
//  * software-pipelined A loads (8-deep const-indexed staging) + v_perm unpack.
// Numerics as rounds 3-5: weights bf16-hi folded, A-side fp32 via bf16 hi/lo
// 2-term MFMA, c/h fp32 in registers, h stored packed (lo16|hi16) u32.

typedef __attribute__((ext_vector_type(8))) short  s16x8;
typedef __attribute__((ext_vector_type(8))) __bf16 bf16x8;
typedef __attribute__((ext_vector_type(4))) float  f32x4;
typedef unsigned long long ull;

__device__ __forceinline__ short f2bfs(float f) {
  union { float f; unsigned u; } v; v.f = f;
  unsigned r = v.u + 0x7FFFu + ((v.u >> 16) & 1u);   // RNE
  return (short)(r >> 16);
}
__device__ __forceinline__ float bf2f(short s) {
  union { unsigned u; float f; } v; v.u = ((unsigned)(unsigned short)s) << 16;
  return v.f;
}
__device__ __forceinline__ void split2(float v, short& hi, short& lo) {
  hi = f2bfs(v);
  lo = f2bfs(v - bf2f(hi));
}
__device__ __forceinline__ float sigf(float x) { return 1.0f / (1.0f + __expf(-x)); }

// 8 packed h values (u32 each) via 4 coherent 8B loads (no fence needed).
__device__ __forceinline__ void load_pk8(const unsigned* p, uint4& r0, uint4& r1) {
  ull u0 = __hip_atomic_load((const ull*)(p),     __ATOMIC_RELAXED, __HIP_MEMORY_SCOPE_AGENT);
  ull u1 = __hip_atomic_load((const ull*)(p + 2), __ATOMIC_RELAXED, __HIP_MEMORY_SCOPE_AGENT);
  ull u2 = __hip_atomic_load((const ull*)(p + 4), __ATOMIC_RELAXED, __HIP_MEMORY_SCOPE_AGENT);
  ull u3 = __hip_atomic_load((const ull*)(p + 6), __ATOMIC_RELAXED, __HIP_MEMORY_SCOPE_AGENT);
  r0 = make_uint4((unsigned)u0, (unsigned)(u0 >> 32), (unsigned)u1, (unsigned)(u1 >> 32));
  r1 = make_uint4((unsigned)u2, (unsigned)(u2 >> 32), (unsigned)u3, (unsigned)(u3 >> 32));
}
// pk = (lo16<<16)|hi16. v_perm: sel bytes 0-3 = src1, 4-7 = src0.
__device__ __forceinline__ void unpack_pk(const uint4 r0, const uint4 r1,
                                          s16x8& hi, s16x8& lo) {
  uint4 hv, lv;
  hv.x = __builtin_amdgcn_perm(r0.y, r0.x, 0x05040100u);
  lv.x = __builtin_amdgcn_perm(r0.y, r0.x, 0x07060302u);
  hv.y = __builtin_amdgcn_perm(r0.w, r0.z, 0x05040100u);
  lv.y = __builtin_amdgcn_perm(r0.w, r0.z, 0x07060302u);
  hv.z = __builtin_amdgcn_perm(r1.y, r1.x, 0x05040100u);
  lv.z = __builtin_amdgcn_perm(r1.y, r1.x, 0x07060302u);
  hv.w = __builtin_amdgcn_perm(r1.w, r1.z, 0x05040100u);
  lv.w = __builtin_amdgcn_perm(r1.w, r1.z, 0x07060302u);
  hi = __builtin_bit_cast(s16x8, hv);
  lo = __builtin_bit_cast(s16x8, lv);
}

__device__ __forceinline__ void unpack8(const uint4 q0, const uint4 q1,
                                        s16x8& hi, s16x8& lo) {
  unpack_pk(q0, q1, hi, lo);
}

// Barrier: 8 sub-counters (8 arrivers each) per rb group; arrive RELEASE,
// spin RELAXED over all 8 (everything shared is sc1 -> no fence needed).
__device__ __forceinline__ void barrier_rb(unsigned* base, int mysub,
                                           unsigned target) {
  __syncthreads();
  if (threadIdx.x == 0) {
    __hip_atomic_fetch_add(base + (mysub << 6), 1u, __ATOMIC_RELEASE,
                           __HIP_MEMORY_SCOPE_AGENT);
    int spins = 0;
    for (;;) {
      unsigned mn = 0xffffffffu;
      #pragma unroll
      for (int q = 0; q < 8; ++q) {
        unsigned v = __hip_atomic_load(base + (q << 6), __ATOMIC_RELAXED,
                                       __HIP_MEMORY_SCOPE_AGENT);
        mn = v < mn ? v : mn;
      }
      if (mn >= target) break;
      __builtin_amdgcn_s_sleep(1);
      if (++spins > (1 << 20)) break;   // safety: never hang
    }
  }
  __builtin_amdgcn_sched_barrier(0);
  __syncthreads();
}

// ---------------------------------------------------------------------------
// Persistent LSTM. wg = [layer(1) | rb(2) | cb(5)], 512 threads = 8 waves:
// wave = kh*4 + ws; kh 0 -> k<512 (+epilogue), kh 1 -> k>=512 (+LDS reduce).
// LDS: 128KB weights (fragment-linear swizzled) + 16KB reduce = 144KB.
// ---------------------------------------------------------------------------
#define REDOFF 131072

__global__ __launch_bounds__(512, 1) void lstm_persist(
    const float* __restrict__ seq,
    unsigned* __restrict__ h0P, unsigned* __restrict__ h1P,
    const short* __restrict__ Wf, const float* __restrict__ biasF,
    const int* __restrict__ slen, unsigned* __restrict__ bar)
{
  extern __shared__ __align__(16) char bsw[];
  const int wg = blockIdx.x;
  const int layer = wg >> 7;
  const int idx = wg & 127;
  const int cb = idx & 31, rb = idx >> 5;          // ensemble e == rb
  const int tid = threadIdx.x;
  const int wave = tid >> 6, lane = tid & 63;
  const int kh = wave >> 2, ws = wave & 3;         // k-half, row-tile
  const int mysub = (layer << 2) | (cb >> 3);      // 8 subs of 8 WGs per rb

  // ---- stage weight slice into LDS, fragment-linear swizzled ----
  const short* Wfe = Wf + ((size_t)(layer * 4 + rb) * 2048 + cb * 64) * 1024;
  #pragma unroll
  for (int i = 0; i < 16; ++i) {
    int f = (i << 9) + tid;                        // 0..8191 fragments
    int col = f >> 7, fr = f & 127;
    s16x8 v = *reinterpret_cast<const s16x8*>(Wfe + (size_t)col * 1024 + (fr << 3));
    int byo = (fr << 10) + (((col << 4)) ^ ((fr & 7) << 4));
    *reinterpret_cast<s16x8*>(bsw + byo) = v;
  }
  __syncthreads();

  const int j = lane & 15;
  const int g = lane >> 4;
  const int koff = g << 3;
  const int rowg = rb * 64 + ws * 16 + j;          // A row for this lane
  const int rbase = rb * 64 + ws * 16 + (g << 2);  // epilogue rows (kh==0)
  const int u = cb * 16 + j;
  const float* bp = biasF + (size_t)(layer * 4 + rb) * 2048 + cb * 64 + j;
  const float bi = bp[0], bff = bp[16], bg = bp[32], bo = bp[48];
  int msl[4];
  #pragma unroll
  for (int r = 0; r < 4; ++r) msl[r] = slen[rbase + r];

  float creg[4] = {0.f, 0.f, 0.f, 0.f};
  float hreg[4] = {0.f, 0.f, 0.f, 0.f};
  const size_t BH = (size_t)256 * 512;
  unsigned* bbase = bar + (rb << 9);
  const int fragbase = kh << 6;                    // kh0: 0..63, kh1: 64..127

  for (int t = 0; t <= 256; ++t) {
    const int s = t - layer;
    if (s >= 0 && s < 256) {
      const int cur = s & 1;
      const unsigned* hPrev = (layer ? h1P : h0P) + (size_t)cur * BH;
      unsigned* hOut = (layer ? h1P : h0P) + (size_t)(cur ^ 1) * BH;

      f32x4 acc[4] = {}, accL[4] = {};

      #define MMQ(FRAG, AHI, ALO)                                             \
        {                                                                     \
          const int fb_ = (FRAG) << 10;                                       \
          const int xm_ = ((FRAG) & 7) << 4;                                  \
          _Pragma("unroll")                                                   \
          for (int cf = 0; cf < 4; ++cf) {                                    \
            const int byo_ = fb_ + ((((cf << 8) | (j << 4))) ^ xm_);          \
            s16x8 b_ = *reinterpret_cast<const s16x8*>(bsw + byo_);           \
            acc[cf] = __builtin_amdgcn_mfma_f32_16x16x32_bf16(                \
                __builtin_bit_cast(bf16x8, AHI),                              \
                __builtin_bit_cast(bf16x8, b_), acc[cf], 0, 0, 0);            \
            accL[cf] = __builtin_amdgcn_mfma_f32_16x16x32_bf16(               \
                __builtin_bit_cast(bf16x8, ALO),                              \
                __builtin_bit_cast(bf16x8, b_), accL[cf], 0, 0, 0);           \
          }                                                                   \
        }

      if (kh == 0 && layer == 0) {
        // x fp32, split on the fly (truncate-hi + RNE residual)
        const float* xr = seq + (size_t)rowg * 131072 + (size_t)s * 512 + koff;
        #pragma unroll
        for (int blk = 0; blk < 2; ++blk) {
          float4 X0[8], X1[8];
          #pragma unroll
          for (int q = 0; q < 8; ++q) {
            const float* p = xr + (((blk << 3) | q) << 5);
            X0[q] = *reinterpret_cast<const float4*>(p);
            X1[q] = *reinterpret_cast<const float4*>(p + 4);
          }
          #pragma unroll
          for (int q = 0; q < 8; ++q) {
            float xv[8] = {X0[q].x, X0[q].y, X0[q].z, X0[q].w,
                           X1[q].x, X1[q].y, X1[q].z, X1[q].w};
            s16x8 ahi, alo;
            #pragma unroll
            for (int e = 0; e < 8; ++e) {
              union { float f; unsigned u; } vv; vv.f = xv[e];
              short h = (short)(vv.u >> 16);
              ahi[e] = h;
              alo[e] = f2bfs(xv[e] - bf2f(h));
            }
            MMQ(((((blk << 3) | q) << 2) | g), ahi, alo)
          }
        }
      } else {
        // packed-h source: kh0/layer1 -> h0 of this step; kh1 -> own prev h
        const unsigned* ap =
            (kh == 0) ? (h0P + (size_t)(cur ^ 1) * BH + (size_t)rowg * 512 + koff)
                      : (hPrev + (size_t)rowg * 512 + koff);
        #pragma unroll
        for (int blk = 0; blk < 2; ++blk) {
          uint4 R0[8], R1[8];
          #pragma unroll
          for (int q = 0; q < 8; ++q)
            load_pk8(ap + (((blk << 3) | q) << 5), R0[q], R1[q]);
          #pragma unroll
          for (int q = 0; q < 8; ++q) {
            s16x8 ahi, alo;
            unpack_pk(R0[q], R1[q], ahi, alo);
            MMQ((fragbase + ((((blk << 3) | q) << 2) | g)), ahi, alo)
          }
        }
      }
      #undef MMQ

      // ---- kh1: deposit partials; kh0: finish cell after sync ----
      if (kh == 1) {
        #pragma unroll
        for (int r = 0; r < 4; ++r) {
          const int lrow = ws * 16 + (g << 2) + r;
          f32x4 v = {acc[0][r] + accL[0][r], acc[1][r] + accL[1][r],
                     acc[2][r] + accL[2][r], acc[3][r] + accL[3][r]};
          *reinterpret_cast<f32x4*>(bsw + REDOFF + lrow * 256 + j * 16) = v;
        }
      }
      __syncthreads();
      if (kh == 0) {
        #pragma unroll
        for (int r = 0; r < 4; ++r) {
          const int lrow = ws * 16 + (g << 2) + r;
          f32x4 red = *reinterpret_cast<const f32x4*>(bsw + REDOFF + lrow * 256 + j * 16);
          const int row = rbase + r;
          float zi = acc[0][r] + accL[0][r] + red[0] + bi;
          float zf = acc[1][r] + accL[1][r] + red[1] + bff;
          float zg = acc[2][r] + accL[2][r] + red[2] + bg;
          float zo = acc[3][r] + accL[3][r] + red[3] + bo;
          float cn = sigf(zf) * creg[r] + sigf(zi) * tanhf(zg);
          float hn = sigf(zo) * tanhf(cn);
          if (s >= msl[r]) { cn = creg[r]; hn = hreg[r]; }   // masked: carry
          creg[r] = cn; hreg[r] = hn;
          short hh, hl; split2(hn, hh, hl);
          unsigned pk = ((unsigned)(unsigned short)hl << 16)
                      | (unsigned)(unsigned short)hh;
          __hip_atomic_store(&hOut[(size_t)row * 512 + u], pk,
                             __ATOMIC_RELAXED, __HIP_MEMORY_SCOPE_AGENT);
        }
      }
    } else {
      __syncthreads();                             // keep barrier sequence uniform
    }
    if (t < 256) barrier_rb(bbase, mysub, 8u * (unsigned)(t + 1));
  }
}

// ---------------------------------------------------------------------------
// Head GEMM: 64x64 tile, B (bf16 hi) from global, packed A, 2-term MFMA.
// EPI 1 = relu6 -> packed hi|lo; EPI 2 = f32 out. (After kernel boundary,
// plain loads see the persistent kernel's sc1 stores.)
// ---------------------------------------------------------------------------
template<int EPI>
__global__ __launch_bounds__(256) void head_gemm(
    const unsigned* __restrict__ a0, int sA0,
    const unsigned* __restrict__ a1, int sA1, int kSplit,
    const short* __restrict__ Wh, const float* __restrict__ bias,
    int N, int K,
    unsigned* __restrict__ outP, float* __restrict__ outf)
{
  const int cb = blockIdx.x, rb = blockIdx.y;     // e == rb
  const int tid = threadIdx.x, wave = tid >> 6, lane = tid & 63;
  const int j = lane & 15;
  const int rowg = rb * 64 + wave * 16 + j;
  const int koff = (lane >> 4) << 3;
  const short* We = Wh + ((size_t)rb * N + cb * 64) * K;
  f32x4 acc[4] = {}, accL[4] = {};
  for (int ks = 0; ks < (K >> 5); ++ks) {
    const int kl = (ks << 5) + koff;
    const unsigned* ap = (kl < kSplit)
        ? (a0 + (size_t)rowg * sA0 + kl)
        : (a1 + (size_t)rowg * sA1 + (kl - kSplit));
    uint4 q0 = *reinterpret_cast<const uint4*>(ap);
    uint4 q1 = *reinterpret_cast<const uint4*>(ap + 4);
    s16x8 ahi, alo; unpack8(q0, q1, ahi, alo);
    #pragma unroll
    for (int cf = 0; cf < 4; ++cf) {
      const int ccol = (cf << 4) + j;
      s16x8 b = *reinterpret_cast<const s16x8*>(We + (size_t)ccol * K + kl);
      acc[cf] = __builtin_amdgcn_mfma_f32_16x16x32_bf16(
          __builtin_bit_cast(bf16x8, ahi), __builtin_bit_cast(bf16x8, b),
          acc[cf], 0, 0, 0);
      accL[cf] = __builtin_amdgcn_mfma_f32_16x16x32_bf16(
          __builtin_bit_cast(bf16x8, alo), __builtin_bit_cast(bf16x8, b),
          accL[cf], 0, 0, 0);
    }
  }
  const int rbase = rb * 64 + wave * 16 + ((lane >> 4) << 2);
  #pragma unroll
  for (int cf = 0; cf < 4; ++cf) {
    const int col = cb * 64 + cf * 16 + j;
    const float bb = bias[(size_t)rb * N + col];
    #pragma unroll
    for (int r = 0; r < 4; ++r) {
      float z = acc[cf][r] + accL[cf][r] + bb;
      if (EPI == 1) {
        z = fminf(fmaxf(z, 0.f), 6.f);
        short hh, hl; split2(z, hh, hl);
        outP[(size_t)(rbase + r) * N + col] =
            ((unsigned)(unsigned short)hl << 16) | (unsigned)(unsigned short)hh;
      } else {
        outf[(size_t)(rbase + r) * N + col] = z;
      }
    }
  }
}

// ---------------------------------------------------------------------------
// Prep kernels (unchanged from round 5).
// ---------------------------------------------------------------------------
__global__ __launch_bounds__(256) void fold_lstm(
    const float* __restrict__ W, const float* __restrict__ U,
    const float* __restrict__ al, const float* __restrict__ ral,
    const float* __restrict__ ga, const float* __restrict__ rga,
    short* __restrict__ Wf)
{
  __shared__ float T[64][65];
  const int tid = threadIdx.x;
  const int kb = blockIdx.x * 64;
  const int cb = blockIdx.y;
  const int le = blockIdx.z;
  const int l  = le >> 2;
  const int kl = tid >> 2;
  const int g  = tid & 3;
  const int k  = kb + kl;
  const bool isW = k < 512;
  const int kk = isW ? k : k - 512;
  const float* src = (isW ? W : U) + ((size_t)l * 512 + kk) * 2048;
  const float  a   = (isW ? al : ral)[(size_t)le * 512 + kk];
  const float* gam = (isW ? ga : rga) + (size_t)le * 2048;
  const int colBase = g * 512 + cb * 16;
  const float4* s4 = reinterpret_cast<const float4*>(src + colBase);
  const float4* g4 = reinterpret_cast<const float4*>(gam + colBase);
  #pragma unroll
  for (int q = 0; q < 4; ++q) {
    float4 v = s4[q], gv = g4[q];
    T[kl][g * 16 + q * 4 + 0] = v.x * a * gv.x;
    T[kl][g * 16 + q * 4 + 1] = v.y * a * gv.y;
    T[kl][g * 16 + q * 4 + 2] = v.z * a * gv.z;
    T[kl][g * 16 + q * 4 + 3] = v.w * a * gv.w;
  }
  __syncthreads();
  const int cl = tid >> 2, kq0 = (tid & 3) * 16;
  alignas(16) short tH[16];
  #pragma unroll
  for (int q = 0; q < 16; ++q) tH[q] = f2bfs(T[kq0 + q][cl]);
  size_t dst = ((size_t)le * 2048 + cb * 64 + cl) * 1024 + kb + kq0;
  *reinterpret_cast<s16x8*>(Wf + dst)     = *reinterpret_cast<s16x8*>(tH);
  *reinterpret_cast<s16x8*>(Wf + dst + 8) = *reinterpret_cast<s16x8*>(tH + 8);
}

__global__ __launch_bounds__(256) void fold_plain(
    const float* __restrict__ src, const float* __restrict__ al,
    const float* __restrict__ ga, short* __restrict__ dst, int N, int K)
{
  __shared__ float T[64][65];
  const int tid = threadIdx.x;
  const int kb = blockIdx.x * 64;
  const int nb = blockIdx.y;
  const int e  = blockIdx.z;
  const int kl = tid >> 2;
  const int c0 = (tid & 3) * 16;
  const int k  = kb + kl;
  const float a = al[(size_t)e * K + k];
  const int colBase = nb * 64 + c0;
  const float4* s4 = reinterpret_cast<const float4*>(src + (size_t)k * N + colBase);
  const float4* g4 = reinterpret_cast<const float4*>(ga + (size_t)e * N + colBase);
  #pragma unroll
  for (int q = 0; q < 4; ++q) {
    float4 v = s4[q], gv = g4[q];
    T[kl][c0 + q * 4 + 0] = v.x * a * gv.x;
    T[kl][c0 + q * 4 + 1] = v.y * a * gv.y;
    T[kl][c0 + q * 4 + 2] = v.z * a * gv.z;
    T[kl][c0 + q * 4 + 3] = v.w * a * gv.w;
  }
  __syncthreads();
  const int cl = tid >> 2, kq0 = (tid & 3) * 16;
  alignas(16) short tH[16];
  #pragma unroll
  for (int q = 0; q < 16; ++q) tH[q] = f2bfs(T[kq0 + q][cl]);
  size_t d = ((size_t)e * N + nb * 64 + cl) * K + kb + kq0;
  *reinterpret_cast<s16x8*>(dst + d)     = *reinterpret_cast<s16x8*>(tH);
  *reinterpret_cast<s16x8*>(dst + d + 8) = *reinterpret_cast<s16x8*>(tH + 8);
}

__global__ void fold_bias_lstm(const float* __restrict__ b, float* __restrict__ bf) {
  int idx = blockIdx.x * 256 + threadIdx.x;          // 16384
  int cp = idx & 2047, le = idx >> 11;
  int ublk = cp >> 6, g = (cp >> 4) & 3, jj = cp & 15;
  bf[idx] = b[(size_t)le * 2048 + g * 512 + ublk * 16 + jj];
}

__global__ void cvt_pack(const float* __restrict__ s,
                         unsigned* __restrict__ d, int n) {
  int i = blockIdx.x * blockDim.x + threadIdx.x;
  if (i < n) {
    short h, l; split2(s[i], h, l);
    d[i] = ((unsigned)(unsigned short)l << 16) | (unsigned)(unsigned short)h;
  }
}

__global__ void zero_ws(float4* p, int n) {
  int i = blockIdx.x * blockDim.x + threadIdx.x;
  if (i < n) p[i] = make_float4(0.f, 0.f, 0.f, 0.f);
}

__global__ void init_bar(unsigned* bar) {
  int i = blockIdx.x * 256 + threadIdx.x;
  if (i < 2048) bar[i] = 0u;
}

// ---------------------------------------------------------------------------
// workspace layout (bytes)
// ---------------------------------------------------------------------------
constexpr size_t OFF_WF    = 0;                      // 2*4*2048*1024*2 = 33554432
constexpr size_t OFF_WHID  = 33554432;               // 4*256*768*2     = 1572864
constexpr size_t OFF_WOUT  = OFF_WHID + 1572864;     // 4*64*256*2      = 131072
constexpr size_t OFF_BIASF = OFF_WOUT + 131072;      // 16384*4         = 65536
constexpr size_t OFF_CTXP  = OFF_BIASF + 65536;      // 65536*4         = 262144
constexpr size_t OFF_H0P   = OFF_CTXP + 262144;      // 2*256*512*4     = 1048576
constexpr size_t OFF_H1P   = OFF_H0P + 1048576;      // 1048576
constexpr size_t OFF_HIDP  = OFF_H1P + 1048576;      // 256*256*4       = 262144
constexpr size_t OFF_BAR   = OFF_HIDP + 262144;      // 8192 (4 rb x 2KB)

extern "C" void kernel_launch(void* const* d_in, const int* in_sizes, int n_in,
                              void* d_out, int out_size, void* d_ws, size_t ws_size,
                              hipStream_t stream) {
  (void)in_sizes; (void)n_in; (void)out_size; (void)ws_size;
  const float* seq  = (const float*)d_in[0];
  const float* ctx  = (const float*)d_in[1];
  const int*   slen = (const int*)d_in[2];
  const float* lW   = (const float*)d_in[3];
  const float* lU   = (const float*)d_in[4];
  const float* lb   = (const float*)d_in[5];
  const float* lal  = (const float*)d_in[6];
  const float* lga  = (const float*)d_in[7];
  const float* lral = (const float*)d_in[8];
  const float* lrga = (const float*)d_in[9];
  const float* hW   = (const float*)d_in[10];
  const float* hb   = (const float*)d_in[11];
  const float* hal  = (const float*)d_in[12];
  const float* hga  = (const float*)d_in[13];
  const float* oW   = (const float*)d_in[14];
  const float* ob   = (const float*)d_in[15];
  const float* oal  = (const float*)d_in[16];
  const float* oga  = (const float*)d_in[17];

  char* ws = (char*)d_ws;
  short*    Wf    = (short*)(ws + OFF_WF);
  short*    Whid  = (short*)(ws + OFF_WHID);
  short*    Wout  = (short*)(ws + OFF_WOUT);
  float*    biasF = (float*)(ws + OFF_BIASF);
  unsigned* ctxP  = (unsigned*)(ws + OFF_CTXP);
  unsigned* h0P   = (unsigned*)(ws + OFF_H0P);
  unsigned* h1P   = (unsigned*)(ws + OFF_H1P);
  unsigned* hidP  = (unsigned*)(ws + OFF_HIDP);
  unsigned* bar   = (unsigned*)(ws + OFF_BAR);

  // allow 144 KiB dynamic LDS
  (void)hipFuncSetAttribute(reinterpret_cast<const void*>(lstm_persist),
                            hipFuncAttributeMaxDynamicSharedMemorySize, 147456);

  // prep (every call: deterministic, no caching)
  fold_lstm<<<dim3(16, 32, 8), 256, 0, stream>>>(lW, lU, lal, lral, lga, lrga, Wf);
  fold_plain<<<dim3(12, 4, 4), 256, 0, stream>>>(hW, hal, hga, Whid, 256, 768);
  fold_plain<<<dim3(4, 1, 4), 256, 0, stream>>>(oW, oal, oga, Wout, 64, 256);
  fold_bias_lstm<<<64, 256, 0, stream>>>(lb, biasF);
  cvt_pack<<<256, 256, 0, stream>>>(ctx, ctxP, 65536);
  zero_ws<<<512, 256, 0, stream>>>((float4*)(ws + OFF_H0P), 2097152 / 16);
  init_bar<<<8, 256, 0, stream>>>(bar);

  // the whole recurrence in one persistent kernel (256 WGs = 1/CU, 8 waves)
  lstm_persist<<<256, 512, 147456, stream>>>(seq, h0P, h1P, Wf, biasF, slen, bar);

  // head: hidden = relu6(((h1,ctx)*a)@hid_W*g + b); out = ((hid*a)@out_W*g + b)
  head_gemm<1><<<dim3(4, 4), 256, 0, stream>>>(
      h1P /* final h1 in buf0 */, 512,
      ctxP, 256, 512,
      Whid, hb, 256, 768, hidP, nullptr);
  head_gemm<2><<<dim3(1, 4), 256, 0, stream>>>(
      hidP, 256,
      hidP, 256, 256,
      Wout, ob, 64, 256,
      nullptr, (float*)d_out);
}

// Round 7
// 4501.270 us; speedup vs baseline: 1.2483x; 1.2483x over previous
//
#include <hip/hip_runtime.h>
#include <cstdint>
#include <cstddef>

// Rank1BayesianRNN on MI355X — round 7: zero-poll tree barrier + packed seq.
// vs round 6 (21.9us/step, MfmaUtil 7.7%): the step was ~75% sync latency.
//  * barrier: cohort(8x8)->root RMW tree, ALL RELAXED; last root arriver IS
//    the releaser (no one polls counters); release = one 64-lane wave store
//    to per-WG flag lines; each WG spins only on its own line.
//  * no RELEASE/ACQUIRE anywhere: h stores sc1 write-through (drained by
//    __syncthreads vmcnt(0) before arrival), h loads sc1 -> coherence point.
//  * seq pre-packed to (lo|hi) u32 once: layer0 A-path == h path, no per-step
//    fp32 split VALU; seq loads plain (L2-cached).
// Numerics as rounds 3-6: weights bf16-hi folded, A-side fp32 via bf16 hi/lo
// 2-term MFMA, c/h fp32 in registers, h packed (lo16|hi16) u32.

typedef __attribute__((ext_vector_type(8))) short  s16x8;
typedef __attribute__((ext_vector_type(8))) __bf16 bf16x8;
typedef __attribute__((ext_vector_type(4))) float  f32x4;
typedef unsigned long long ull;

__device__ __forceinline__ short f2bfs(float f) {
  union { float f; unsigned u; } v; v.f = f;
  unsigned r = v.u + 0x7FFFu + ((v.u >> 16) & 1u);   // RNE
  return (short)(r >> 16);
}
__device__ __forceinline__ float bf2f(short s) {
  union { unsigned u; float f; } v; v.u = ((unsigned)(unsigned short)s) << 16;
  return v.f;
}
__device__ __forceinline__ void split2(float v, short& hi, short& lo) {
  hi = f2bfs(v);
  lo = f2bfs(v - bf2f(hi));
}
__device__ __forceinline__ float sigf(float x) { return 1.0f / (1.0f + __expf(-x)); }

// 8 packed values via 4 coherent 8B loads (sc1: served at coherence point).
__device__ __forceinline__ void load_pk8_sc1(const unsigned* p, uint4& r0, uint4& r1) {
  ull u0 = __hip_atomic_load((const ull*)(p),     __ATOMIC_RELAXED, __HIP_MEMORY_SCOPE_AGENT);
  ull u1 = __hip_atomic_load((const ull*)(p + 2), __ATOMIC_RELAXED, __HIP_MEMORY_SCOPE_AGENT);
  ull u2 = __hip_atomic_load((const ull*)(p + 4), __ATOMIC_RELAXED, __HIP_MEMORY_SCOPE_AGENT);
  ull u3 = __hip_atomic_load((const ull*)(p + 6), __ATOMIC_RELAXED, __HIP_MEMORY_SCOPE_AGENT);
  r0 = make_uint4((unsigned)u0, (unsigned)(u0 >> 32), (unsigned)u1, (unsigned)(u1 >> 32));
  r1 = make_uint4((unsigned)u2, (unsigned)(u2 >> 32), (unsigned)u3, (unsigned)(u3 >> 32));
}
// pk = (lo16<<16)|hi16. v_perm: sel bytes 0-3 = src1, 4-7 = src0.
__device__ __forceinline__ void unpack_pk(const uint4 r0, const uint4 r1,
                                          s16x8& hi, s16x8& lo) {
  uint4 hv, lv;
  hv.x = __builtin_amdgcn_perm(r0.y, r0.x, 0x05040100u);
  lv.x = __builtin_amdgcn_perm(r0.y, r0.x, 0x07060302u);
  hv.y = __builtin_amdgcn_perm(r0.w, r0.z, 0x05040100u);
  lv.y = __builtin_amdgcn_perm(r0.w, r0.z, 0x07060302u);
  hv.z = __builtin_amdgcn_perm(r1.y, r1.x, 0x05040100u);
  lv.z = __builtin_amdgcn_perm(r1.y, r1.x, 0x07060302u);
  hv.w = __builtin_amdgcn_perm(r1.w, r1.z, 0x05040100u);
  lv.w = __builtin_amdgcn_perm(r1.w, r1.z, 0x07060302u);
  hi = __builtin_bit_cast(s16x8, hv);
  lo = __builtin_bit_cast(s16x8, lv);
}

// Zero-poll barrier over one rb group (64 WGs), all RELAXED.
// rbBase u32 layout: cohort c at [c*16] (8), root at [128], flag of WG w at
// [256 + w*16]. tstep = t+1 (monotonic, no resets).
__device__ __forceinline__ void barrier_rb(unsigned* rbBase, int wgLocal,
                                           unsigned tstep) {
  __syncthreads();                         // drains vmcnt: h stores at L3
  if (threadIdx.x < 64) {                  // wave 0 runs the protocol
    const int lane = threadIdx.x;
    int rel = 0;
    if (lane == 0) {
      const int c = wgLocal >> 3;
      unsigned a = __hip_atomic_fetch_add(rbBase + c * 16, 1u,
                                          __ATOMIC_RELAXED, __HIP_MEMORY_SCOPE_AGENT);
      if (a == 8u * tstep - 1u) {          // cohort complete
        unsigned r = __hip_atomic_fetch_add(rbBase + 128, 1u,
                                            __ATOMIC_RELAXED, __HIP_MEMORY_SCOPE_AGENT);
        if (r == 8u * tstep - 1u) rel = 1; // all 8 cohorts: I am the releaser
      }
    }
    rel = __shfl(rel, 0);
    unsigned* flags = rbBase + 256;
    if (rel) {
      // one wave store: lane i releases WG i of this rb group
      __hip_atomic_store(flags + lane * 16, tstep,
                         __ATOMIC_RELAXED, __HIP_MEMORY_SCOPE_AGENT);
    } else if (lane == 0) {
      int spins = 0;
      while (__hip_atomic_load(flags + wgLocal * 16, __ATOMIC_RELAXED,
                               __HIP_MEMORY_SCOPE_AGENT) < tstep) {
        __builtin_amdgcn_s_sleep(1);
        if (++spins > (1 << 22)) break;    // safety: never hang
      }
    }
  }
  __syncthreads();
}

// ---------------------------------------------------------------------------
// Persistent LSTM. wg = [layer(1) | rb(2) | cb(5)], 512 threads = 8 waves:
// wave = kh*4 + ws; kh 0 -> k<512 (+cell epilogue), kh 1 -> k>=512 (+LDS
// reduce). LDS: 128KB weights (fragment-linear swizzled) + 16KB reduce.
// ---------------------------------------------------------------------------
#define REDOFF 131072

__global__ __launch_bounds__(512, 1) void lstm_persist(
    const unsigned* __restrict__ seqP,
    unsigned* __restrict__ h0P, unsigned* __restrict__ h1P,
    const short* __restrict__ Wf, const float* __restrict__ biasF,
    const int* __restrict__ slen, unsigned* __restrict__ bar)
{
  extern __shared__ __align__(16) char bsw[];
  const int wg = blockIdx.x;
  const int layer = wg >> 7;
  const int idx = wg & 127;
  const int cb = idx & 31, rb = idx >> 5;          // ensemble e == rb
  const int tid = threadIdx.x;
  const int wave = tid >> 6, lane = tid & 63;
  const int kh = wave >> 2, ws = wave & 3;         // k-half, row-tile
  const int wgLocal = (layer << 5) | cb;           // 0..63 within rb group

  // ---- stage weight slice into LDS, fragment-linear swizzled ----
  const short* Wfe = Wf + ((size_t)(layer * 4 + rb) * 2048 + cb * 64) * 1024;
  #pragma unroll
  for (int i = 0; i < 16; ++i) {
    int f = (i << 9) + tid;                        // 0..8191 fragments
    int col = f >> 7, fr = f & 127;
    s16x8 v = *reinterpret_cast<const s16x8*>(Wfe + (size_t)col * 1024 + (fr << 3));
    int byo = (fr << 10) + (((col << 4)) ^ ((fr & 7) << 4));
    *reinterpret_cast<s16x8*>(bsw + byo) = v;
  }
  __syncthreads();

  const int j = lane & 15;
  const int g = lane >> 4;
  const int koff = g << 3;
  const int rowg = rb * 64 + ws * 16 + j;          // A row for this lane
  const int rbase = rb * 64 + ws * 16 + (g << 2);  // epilogue rows (kh==0)
  const int u = cb * 16 + j;
  const float* bp = biasF + (size_t)(layer * 4 + rb) * 2048 + cb * 64 + j;
  const float bi = bp[0], bff = bp[16], bg = bp[32], bo = bp[48];
  int msl[4];
  #pragma unroll
  for (int r = 0; r < 4; ++r) msl[r] = slen[rbase + r];

  float creg[4] = {0.f, 0.f, 0.f, 0.f};
  float hreg[4] = {0.f, 0.f, 0.f, 0.f};
  const size_t BH = (size_t)256 * 512;
  unsigned* rbBase = bar + (rb << 11);             // 8KB per rb group
  const int fragbase = kh << 6;                    // kh0: 0..63, kh1: 64..127

  for (int t = 0; t <= 256; ++t) {
    const int s = t - layer;
    if (s >= 0 && s < 256) {
      const int cur = s & 1;
      const unsigned* hPrev = (layer ? h1P : h0P) + (size_t)cur * BH;
      unsigned* hOut = (layer ? h1P : h0P) + (size_t)(cur ^ 1) * BH;

      f32x4 acc[4] = {}, accL[4] = {};

      #define MMQ(FRAG, AHI, ALO)                                             \
        {                                                                     \
          const int fb_ = (FRAG) << 10;                                       \
          const int xm_ = ((FRAG) & 7) << 4;                                  \
          _Pragma("unroll")                                                   \
          for (int cf = 0; cf < 4; ++cf) {                                    \
            const int byo_ = fb_ + ((((cf << 8) | (j << 4))) ^ xm_);          \
            s16x8 b_ = *reinterpret_cast<const s16x8*>(bsw + byo_);           \
            acc[cf] = __builtin_amdgcn_mfma_f32_16x16x32_bf16(                \
                __builtin_bit_cast(bf16x8, AHI),                              \
                __builtin_bit_cast(bf16x8, b_), acc[cf], 0, 0, 0);            \
            accL[cf] = __builtin_amdgcn_mfma_f32_16x16x32_bf16(               \
                __builtin_bit_cast(bf16x8, ALO),                              \
                __builtin_bit_cast(bf16x8, b_), accL[cf], 0, 0, 0);           \
          }                                                                   \
        }

      if (kh == 0 && layer == 0) {
        // packed x (plain loads, L2-cached)
        const unsigned* ap = seqP + (size_t)rowg * 131072 + (size_t)s * 512 + koff;
        #pragma unroll
        for (int blk = 0; blk < 2; ++blk) {
          uint4 R0[8], R1[8];
          #pragma unroll
          for (int q = 0; q < 8; ++q) {
            const unsigned* p = ap + (((blk << 3) | q) << 5);
            R0[q] = *reinterpret_cast<const uint4*>(p);
            R1[q] = *reinterpret_cast<const uint4*>(p + 4);
          }
          #pragma unroll
          for (int q = 0; q < 8; ++q) {
            s16x8 ahi, alo;
            unpack_pk(R0[q], R1[q], ahi, alo);
            MMQ(((((blk << 3) | q) << 2) | g), ahi, alo)
          }
        }
      } else {
        // coherent packed-h source: kh0/layer1 -> h0 of this step;
        // kh1 -> own layer's previous h.
        const unsigned* ap =
            (kh == 0) ? (h0P + (size_t)(cur ^ 1) * BH + (size_t)rowg * 512 + koff)
                      : (hPrev + (size_t)rowg * 512 + koff);
        #pragma unroll
        for (int blk = 0; blk < 2; ++blk) {
          uint4 R0[8], R1[8];
          #pragma unroll
          for (int q = 0; q < 8; ++q)
            load_pk8_sc1(ap + (((blk << 3) | q) << 5), R0[q], R1[q]);
          #pragma unroll
          for (int q = 0; q < 8; ++q) {
            s16x8 ahi, alo;
            unpack_pk(R0[q], R1[q], ahi, alo);
            MMQ((fragbase + ((((blk << 3) | q) << 2) | g)), ahi, alo)
          }
        }
      }
      #undef MMQ

      // ---- kh1: deposit partials; kh0: finish cell after sync ----
      if (kh == 1) {
        #pragma unroll
        for (int r = 0; r < 4; ++r) {
          const int lrow = ws * 16 + (g << 2) + r;
          f32x4 v = {acc[0][r] + accL[0][r], acc[1][r] + accL[1][r],
                     acc[2][r] + accL[2][r], acc[3][r] + accL[3][r]};
          *reinterpret_cast<f32x4*>(bsw + REDOFF + lrow * 256 + j * 16) = v;
        }
      }
      __syncthreads();
      if (kh == 0) {
        #pragma unroll
        for (int r = 0; r < 4; ++r) {
          const int lrow = ws * 16 + (g << 2) + r;
          f32x4 red = *reinterpret_cast<const f32x4*>(bsw + REDOFF + lrow * 256 + j * 16);
          const int row = rbase + r;
          float zi = acc[0][r] + accL[0][r] + red[0] + bi;
          float zf = acc[1][r] + accL[1][r] + red[1] + bff;
          float zg = acc[2][r] + accL[2][r] + red[2] + bg;
          float zo = acc[3][r] + accL[3][r] + red[3] + bo;
          float cn = sigf(zf) * creg[r] + sigf(zi) * tanhf(zg);
          float hn = sigf(zo) * tanhf(cn);
          if (s >= msl[r]) { cn = creg[r]; hn = hreg[r]; }   // masked: carry
          creg[r] = cn; hreg[r] = hn;
          short hh, hl; split2(hn, hh, hl);
          unsigned pk = ((unsigned)(unsigned short)hl << 16)
                      | (unsigned)(unsigned short)hh;
          __hip_atomic_store(&hOut[(size_t)row * 512 + u], pk,
                             __ATOMIC_RELAXED, __HIP_MEMORY_SCOPE_AGENT);
        }
      }
    }
    if (t < 256) barrier_rb(rbBase, wgLocal, (unsigned)(t + 1));
  }
}

// ---------------------------------------------------------------------------
// Head GEMM: 64x64 tile, B (bf16 hi) from global, packed A, 2-term MFMA.
// EPI 1 = relu6 -> packed hi|lo; EPI 2 = f32 out.
// ---------------------------------------------------------------------------
template<int EPI>
__global__ __launch_bounds__(256) void head_gemm(
    const unsigned* __restrict__ a0, int sA0,
    const unsigned* __restrict__ a1, int sA1, int kSplit,
    const short* __restrict__ Wh, const float* __restrict__ bias,
    int N, int K,
    unsigned* __restrict__ outP, float* __restrict__ outf)
{
  const int cb = blockIdx.x, rb = blockIdx.y;     // e == rb
  const int tid = threadIdx.x, wave = tid >> 6, lane = tid & 63;
  const int j = lane & 15;
  const int rowg = rb * 64 + wave * 16 + j;
  const int koff = (lane >> 4) << 3;
  const short* We = Wh + ((size_t)rb * N + cb * 64) * K;
  f32x4 acc[4] = {}, accL[4] = {};
  for (int ks = 0; ks < (K >> 5); ++ks) {
    const int kl = (ks << 5) + koff;
    const unsigned* ap = (kl < kSplit)
        ? (a0 + (size_t)rowg * sA0 + kl)
        : (a1 + (size_t)rowg * sA1 + (kl - kSplit));
    uint4 q0 = *reinterpret_cast<const uint4*>(ap);
    uint4 q1 = *reinterpret_cast<const uint4*>(ap + 4);
    s16x8 ahi, alo; unpack_pk(q0, q1, ahi, alo);
    #pragma unroll
    for (int cf = 0; cf < 4; ++cf) {
      const int ccol = (cf << 4) + j;
      s16x8 b = *reinterpret_cast<const s16x8*>(We + (size_t)ccol * K + kl);
      acc[cf] = __builtin_amdgcn_mfma_f32_16x16x32_bf16(
          __builtin_bit_cast(bf16x8, ahi), __builtin_bit_cast(bf16x8, b),
          acc[cf], 0, 0, 0);
      accL[cf] = __builtin_amdgcn_mfma_f32_16x16x32_bf16(
          __builtin_bit_cast(bf16x8, alo), __builtin_bit_cast(bf16x8, b),
          accL[cf], 0, 0, 0);
    }
  }
  const int rbase = rb * 64 + wave * 16 + ((lane >> 4) << 2);
  #pragma unroll
  for (int cf = 0; cf < 4; ++cf) {
    const int col = cb * 64 + cf * 16 + j;
    const float bb = bias[(size_t)rb * N + col];
    #pragma unroll
    for (int r = 0; r < 4; ++r) {
      float z = acc[cf][r] + accL[cf][r] + bb;
      if (EPI == 1) {
        z = fminf(fmaxf(z, 0.f), 6.f);
        short hh, hl; split2(z, hh, hl);
        outP[(size_t)(rbase + r) * N + col] =
            ((unsigned)(unsigned short)hl << 16) | (unsigned)(unsigned short)hh;
      } else {
        outf[(size_t)(rbase + r) * N + col] = z;
      }
    }
  }
}

// ---------------------------------------------------------------------------
// Prep kernels.
// ---------------------------------------------------------------------------
__global__ __launch_bounds__(256) void fold_lstm(
    const float* __restrict__ W, const float* __restrict__ U,
    const float* __restrict__ al, const float* __restrict__ ral,
    const float* __restrict__ ga, const float* __restrict__ rga,
    short* __restrict__ Wf)
{
  __shared__ float T[64][65];
  const int tid = threadIdx.x;
  const int kb = blockIdx.x * 64;
  const int cb = blockIdx.y;
  const int le = blockIdx.z;
  const int l  = le >> 2;
  const int kl = tid >> 2;
  const int g  = tid & 3;
  const int k  = kb + kl;
  const bool isW = k < 512;
  const int kk = isW ? k : k - 512;
  const float* src = (isW ? W : U) + ((size_t)l * 512 + kk) * 2048;
  const float  a   = (isW ? al : ral)[(size_t)le * 512 + kk];
  const float* gam = (isW ? ga : rga) + (size_t)le * 2048;
  const int colBase = g * 512 + cb * 16;
  const float4* s4 = reinterpret_cast<const float4*>(src + colBase);
  const float4* g4 = reinterpret_cast<const float4*>(gam + colBase);
  #pragma unroll
  for (int q = 0; q < 4; ++q) {
    float4 v = s4[q], gv = g4[q];
    T[kl][g * 16 + q * 4 + 0] = v.x * a * gv.x;
    T[kl][g * 16 + q * 4 + 1] = v.y * a * gv.y;
    T[kl][g * 16 + q * 4 + 2] = v.z * a * gv.z;
    T[kl][g * 16 + q * 4 + 3] = v.w * a * gv.w;
  }
  __syncthreads();
  const int cl = tid >> 2, kq0 = (tid & 3) * 16;
  alignas(16) short tH[16];
  #pragma unroll
  for (int q = 0; q < 16; ++q) tH[q] = f2bfs(T[kq0 + q][cl]);
  size_t dst = ((size_t)le * 2048 + cb * 64 + cl) * 1024 + kb + kq0;
  *reinterpret_cast<s16x8*>(Wf + dst)     = *reinterpret_cast<s16x8*>(tH);
  *reinterpret_cast<s16x8*>(Wf + dst + 8) = *reinterpret_cast<s16x8*>(tH + 8);
}

__global__ __launch_bounds__(256) void fold_plain(
    const float* __restrict__ src, const float* __restrict__ al,
    const float* __restrict__ ga, short* __restrict__ dst, int N, int K)
{
  __shared__ float T[64][65];
  const int tid = threadIdx.x;
  const int kb = blockIdx.x * 64;
  const int nb = blockIdx.y;
  const int e  = blockIdx.z;
  const int kl = tid >> 2;
  const int c0 = (tid & 3) * 16;
  const int k  = kb + kl;
  const float a = al[(size_t)e * K + k];
  const int colBase = nb * 64 + c0;
  const float4* s4 = reinterpret_cast<const float4*>(src + (size_t)k * N + colBase);
  const float4* g4 = reinterpret_cast<const float4*>(ga + (size_t)e * N + colBase);
  #pragma unroll
  for (int q = 0; q < 4; ++q) {
    float4 v = s4[q], gv = g4[q];
    T[kl][c0 + q * 4 + 0] = v.x * a * gv.x;
    T[kl][c0 + q * 4 + 1] = v.y * a * gv.y;
    T[kl][c0 + q * 4 + 2] = v.z * a * gv.z;
    T[kl][c0 + q * 4 + 3] = v.w * a * gv.w;
  }
  __syncthreads();
  const int cl = tid >> 2, kq0 = (tid & 3) * 16;
  alignas(16) short tH[16];
  #pragma unroll
  for (int q = 0; q < 16; ++q) tH[q] = f2bfs(T[kq0 + q][cl]);
  size_t d = ((size_t)e * N + nb * 64 + cl) * K + kb + kq0;
  *reinterpret_cast<s16x8*>(dst + d)     = *reinterpret_cast<s16x8*>(tH);
  *reinterpret_cast<s16x8*>(dst + d + 8) = *reinterpret_cast<s16x8*>(tH + 8);
}

__global__ void fold_bias_lstm(const float* __restrict__ b, float* __restrict__ bf) {
  int idx = blockIdx.x * 256 + threadIdx.x;          // 16384
  int cp = idx & 2047, le = idx >> 11;
  int ublk = cp >> 6, g = (cp >> 4) & 3, jj = cp & 15;
  bf[idx] = b[(size_t)le * 2048 + g * 512 + ublk * 16 + jj];
}

__global__ void cvt_pack(const float* __restrict__ s,
                         unsigned* __restrict__ d, int n) {
  int i = blockIdx.x * blockDim.x + threadIdx.x;
  if (i < n) {
    short h, l; split2(s[i], h, l);
    d[i] = ((unsigned)(unsigned short)l << 16) | (unsigned)(unsigned short)h;
  }
}

// seq -> packed (lo|hi) u32, 4 elements/thread
__global__ void pack_seq(const float* __restrict__ s, unsigned* __restrict__ d) {
  int i = (blockIdx.x * 256 + threadIdx.x) * 4;
  float4 v = *reinterpret_cast<const float4*>(s + i);
  uint4 o;
  short h, l;
  split2(v.x, h, l); o.x = ((unsigned)(unsigned short)l << 16) | (unsigned)(unsigned short)h;
  split2(v.y, h, l); o.y = ((unsigned)(unsigned short)l << 16) | (unsigned)(unsigned short)h;
  split2(v.z, h, l); o.z = ((unsigned)(unsigned short)l << 16) | (unsigned)(unsigned short)h;
  split2(v.w, h, l); o.w = ((unsigned)(unsigned short)l << 16) | (unsigned)(unsigned short)h;
  *reinterpret_cast<uint4*>(d + i) = o;
}

__global__ void zero_ws(float4* p, int n) {
  int i = blockIdx.x * blockDim.x + threadIdx.x;
  if (i < n) p[i] = make_float4(0.f, 0.f, 0.f, 0.f);
}

__global__ void init_bar(unsigned* bar) {
  int i = blockIdx.x * 256 + threadIdx.x;
  if (i < 8192) bar[i] = 0u;
}

// ---------------------------------------------------------------------------
// workspace layout (bytes)
// ---------------------------------------------------------------------------
constexpr size_t OFF_WF    = 0;                      // 2*4*2048*1024*2 = 33554432
constexpr size_t OFF_WHID  = 33554432;               // 4*256*768*2     = 1572864
constexpr size_t OFF_WOUT  = OFF_WHID + 1572864;     // 4*64*256*2      = 131072
constexpr size_t OFF_BIASF = OFF_WOUT + 131072;      // 16384*4         = 65536
constexpr size_t OFF_CTXP  = OFF_BIASF + 65536;      // 65536*4         = 262144
constexpr size_t OFF_H0P   = OFF_CTXP + 262144;      // 2*256*512*4     = 1048576
constexpr size_t OFF_H1P   = OFF_H0P + 1048576;      // 1048576
constexpr size_t OFF_HIDP  = OFF_H1P + 1048576;      // 256*256*4       = 262144
constexpr size_t OFF_BAR   = OFF_HIDP + 262144;      // 32768 (4 rb x 8KB)
constexpr size_t OFF_SEQP  = OFF_BAR + 32768;        // 33554432*4 = 134217728

extern "C" void kernel_launch(void* const* d_in, const int* in_sizes, int n_in,
                              void* d_out, int out_size, void* d_ws, size_t ws_size,
                              hipStream_t stream) {
  (void)in_sizes; (void)n_in; (void)out_size; (void)ws_size;
  const float* seq  = (const float*)d_in[0];
  const float* ctx  = (const float*)d_in[1];
  const int*   slen = (const int*)d_in[2];
  const float* lW   = (const float*)d_in[3];
  const float* lU   = (const float*)d_in[4];
  const float* lb   = (const float*)d_in[5];
  const float* lal  = (const float*)d_in[6];
  const float* lga  = (const float*)d_in[7];
  const float* lral = (const float*)d_in[8];
  const float* lrga = (const float*)d_in[9];
  const float* hW   = (const float*)d_in[10];
  const float* hb   = (const float*)d_in[11];
  const float* hal  = (const float*)d_in[12];
  const float* hga  = (const float*)d_in[13];
  const float* oW   = (const float*)d_in[14];
  const float* ob   = (const float*)d_in[15];
  const float* oal  = (const float*)d_in[16];
  const float* oga  = (const float*)d_in[17];

  char* ws = (char*)d_ws;
  short*    Wf    = (short*)(ws + OFF_WF);
  short*    Whid  = (short*)(ws + OFF_WHID);
  short*    Wout  = (short*)(ws + OFF_WOUT);
  float*    biasF = (float*)(ws + OFF_BIASF);
  unsigned* ctxP  = (unsigned*)(ws + OFF_CTXP);
  unsigned* h0P   = (unsigned*)(ws + OFF_H0P);
  unsigned* h1P   = (unsigned*)(ws + OFF_H1P);
  unsigned* hidP  = (unsigned*)(ws + OFF_HIDP);
  unsigned* bar   = (unsigned*)(ws + OFF_BAR);
  unsigned* seqP  = (unsigned*)(ws + OFF_SEQP);

  // allow 144 KiB dynamic LDS
  (void)hipFuncSetAttribute(reinterpret_cast<const void*>(lstm_persist),
                            hipFuncAttributeMaxDynamicSharedMemorySize, 147456);

  // prep (every call: deterministic, no caching)
  fold_lstm<<<dim3(16, 32, 8), 256, 0, stream>>>(lW, lU, lal, lral, lga, lrga, Wf);
  fold_plain<<<dim3(12, 4, 4), 256, 0, stream>>>(hW, hal, hga, Whid, 256, 768);
  fold_plain<<<dim3(4, 1, 4), 256, 0, stream>>>(oW, oal, oga, Wout, 64, 256);
  fold_bias_lstm<<<64, 256, 0, stream>>>(lb, biasF);
  cvt_pack<<<256, 256, 0, stream>>>(ctx, ctxP, 65536);
  pack_seq<<<32768, 256, 0, stream>>>(seq, seqP);
  zero_ws<<<512, 256, 0, stream>>>((float4*)(ws + OFF_H0P), 2097152 / 16);
  init_bar<<<32, 256, 0, stream>>>(bar);

  // the whole recurrence in one persistent kernel (256 WGs = 1/CU, 8 waves)
  lstm_persist<<<256, 512, 147456, stream>>>(seqP, h0P, h1P, Wf, biasF, slen, bar);

  // head: hidden = relu6(((h1,ctx)*a)@hid_W*g + b); out = ((hid*a)@out_W*g + b)
  head_gemm<1><<<dim3(4, 4), 256, 0, stream>>>(
      h1P /* final h1 in buf0 */, 512,
      ctxP, 256, 512,
      Whid, hb, 256, 768, hidP, nullptr);
  head_gemm<2><<<dim3(1, 4), 256, 0, stream>>>(
      hidP, 256,
      hidP, 256, 256,
      Wout, ob, 64, 256,
      nullptr, (float*)d_out);
}

// Round 8
// 3149.156 us; speedup vs baseline: 1.7843x; 1.4294x over previous
//
#include <hip/hip_runtime.h>
#include <cstdint>
#include <cstddef>

// Rank1BayesianRNN on MI355X — round 8: kill the seq HBM refetch + cache h.
// vs round 7 (17.8us/step, FETCH 1.6GB = 12.5x seq size):
//  * seq pre-packed TIME-MAJOR [t][row][512]: per-step slice contiguous,
//    each HBM line fetched once (128MB total, was 1.6GB).
//  * XCD-affine roles: (layer,rb) = blockIdx&7, cb = blockIdx>>3 -> under
//    round-robin dispatch each XCD hosts one (layer,rb) group; its 32 WGs
//    share the same seq/h rows in L2 (perf heuristic only).
//  * h reads = plain cacheable uint4 loads; ONE agent-acquire fence per step
//    (round-5-proven). h stores stay sc1 write-through (drained pre-arrive).
//  * round-7 zero-poll tree barrier kept (all RELAXED, per-WG flag lines).
// Numerics as rounds 3-7: weights bf16-hi folded, A-side fp32 via bf16 hi/lo
// 2-term MFMA, c/h fp32 in registers, h packed (lo16|hi16) u32.

typedef __attribute__((ext_vector_type(8))) short  s16x8;
typedef __attribute__((ext_vector_type(8))) __bf16 bf16x8;
typedef __attribute__((ext_vector_type(4))) float  f32x4;
typedef unsigned long long ull;

__device__ __forceinline__ short f2bfs(float f) {
  union { float f; unsigned u; } v; v.f = f;
  unsigned r = v.u + 0x7FFFu + ((v.u >> 16) & 1u);   // RNE
  return (short)(r >> 16);
}
__device__ __forceinline__ float bf2f(short s) {
  union { unsigned u; float f; } v; v.u = ((unsigned)(unsigned short)s) << 16;
  return v.f;
}
__device__ __forceinline__ void split2(float v, short& hi, short& lo) {
  hi = f2bfs(v);
  lo = f2bfs(v - bf2f(hi));
}
__device__ __forceinline__ float sigf(float x) { return 1.0f / (1.0f + __expf(-x)); }

// pk = (lo16<<16)|hi16. v_perm: sel bytes 0-3 = src1, 4-7 = src0.
__device__ __forceinline__ void unpack_pk(const uint4 r0, const uint4 r1,
                                          s16x8& hi, s16x8& lo) {
  uint4 hv, lv;
  hv.x = __builtin_amdgcn_perm(r0.y, r0.x, 0x05040100u);
  lv.x = __builtin_amdgcn_perm(r0.y, r0.x, 0x07060302u);
  hv.y = __builtin_amdgcn_perm(r0.w, r0.z, 0x05040100u);
  lv.y = __builtin_amdgcn_perm(r0.w, r0.z, 0x07060302u);
  hv.z = __builtin_amdgcn_perm(r1.y, r1.x, 0x05040100u);
  lv.z = __builtin_amdgcn_perm(r1.y, r1.x, 0x07060302u);
  hv.w = __builtin_amdgcn_perm(r1.w, r1.z, 0x05040100u);
  lv.w = __builtin_amdgcn_perm(r1.w, r1.z, 0x07060302u);
  hi = __builtin_bit_cast(s16x8, hv);
  lo = __builtin_bit_cast(s16x8, lv);
}

// Zero-poll tree barrier over one rb group (64 WGs), all RELAXED, then ONE
// agent-acquire fence (L1/L2 inv) so plain loads see the fresh h (stores
// are sc1 write-through, drained by the pre-arrive __syncthreads).
// rbBase u32 layout: cohort c at [c*16] (8), root at [128], flag of WG w at
// [256 + w*16]. tstep = t+1 (monotonic, no resets).
__device__ __forceinline__ void barrier_rb(unsigned* rbBase, int wgLocal,
                                           unsigned tstep) {
  __syncthreads();                         // drains vmcnt: h stores at L3
  if (threadIdx.x < 64) {                  // wave 0 runs the protocol
    const int lane = threadIdx.x;
    int rel = 0;
    if (lane == 0) {
      const int c = wgLocal >> 3;
      unsigned a = __hip_atomic_fetch_add(rbBase + c * 16, 1u,
                                          __ATOMIC_RELAXED, __HIP_MEMORY_SCOPE_AGENT);
      if (a == 8u * tstep - 1u) {          // cohort complete
        unsigned r = __hip_atomic_fetch_add(rbBase + 128, 1u,
                                            __ATOMIC_RELAXED, __HIP_MEMORY_SCOPE_AGENT);
        if (r == 8u * tstep - 1u) rel = 1; // all 8 cohorts: I am the releaser
      }
    }
    rel = __shfl(rel, 0);
    unsigned* flags = rbBase + 256;
    if (rel) {
      // one wave store: lane i releases WG i of this rb group
      __hip_atomic_store(flags + lane * 16, tstep,
                         __ATOMIC_RELAXED, __HIP_MEMORY_SCOPE_AGENT);
    } else if (lane == 0) {
      int spins = 0;
      while (__hip_atomic_load(flags + wgLocal * 16, __ATOMIC_RELAXED,
                               __HIP_MEMORY_SCOPE_AGENT) < tstep) {
        __builtin_amdgcn_s_sleep(1);
        if (++spins > (1 << 22)) break;    // safety: never hang
      }
    }
    if (lane == 0)
      __builtin_amdgcn_fence(__ATOMIC_ACQUIRE, "agent");  // one buffer_inv/CU
  }
  __syncthreads();
}

// ---------------------------------------------------------------------------
// Persistent LSTM. XCD-affine decode: (layer,rb) = wg&7, cb = wg>>3.
// 512 threads = 8 waves: wave = kh*4 + ws; kh 0 -> k<512 (+cell epilogue),
// kh 1 -> k>=512 (+LDS reduce). LDS: 128KB weights + 16KB reduce.
// ---------------------------------------------------------------------------
#define REDOFF 131072

__global__ __launch_bounds__(512, 1) void lstm_persist(
    const unsigned* __restrict__ seqP,     // time-major [t][row][512]
    unsigned* __restrict__ h0P, unsigned* __restrict__ h1P,
    const short* __restrict__ Wf, const float* __restrict__ biasF,
    const int* __restrict__ slen, unsigned* __restrict__ bar)
{
  extern __shared__ __align__(16) char bsw[];
  const int wg = blockIdx.x;
  const int cls = wg & 7;                          // XCD affinity class
  const int layer = cls >> 2;
  const int rb = cls & 3;                          // ensemble e == rb
  const int cb = wg >> 3;                          // 0..31
  const int tid = threadIdx.x;
  const int wave = tid >> 6, lane = tid & 63;
  const int kh = wave >> 2, ws = wave & 3;         // k-half, row-tile
  const int wgLocal = (layer << 5) | cb;           // 0..63 within rb group

  // ---- stage weight slice into LDS, fragment-linear swizzled ----
  const short* Wfe = Wf + ((size_t)(layer * 4 + rb) * 2048 + cb * 64) * 1024;
  #pragma unroll
  for (int i = 0; i < 16; ++i) {
    int f = (i << 9) + tid;                        // 0..8191 fragments
    int col = f >> 7, fr = f & 127;
    s16x8 v = *reinterpret_cast<const s16x8*>(Wfe + (size_t)col * 1024 + (fr << 3));
    int byo = (fr << 10) + (((col << 4)) ^ ((fr & 7) << 4));
    *reinterpret_cast<s16x8*>(bsw + byo) = v;
  }
  __syncthreads();

  const int j = lane & 15;
  const int g = lane >> 4;
  const int koff = g << 3;
  const int rowg = rb * 64 + ws * 16 + j;          // A row for this lane
  const int rbase = rb * 64 + ws * 16 + (g << 2);  // epilogue rows (kh==0)
  const int u = cb * 16 + j;
  const float* bp = biasF + (size_t)(layer * 4 + rb) * 2048 + cb * 64 + j;
  const float bi = bp[0], bff = bp[16], bg = bp[32], bo = bp[48];
  int msl[4];
  #pragma unroll
  for (int r = 0; r < 4; ++r) msl[r] = slen[rbase + r];

  float creg[4] = {0.f, 0.f, 0.f, 0.f};
  float hreg[4] = {0.f, 0.f, 0.f, 0.f};
  const size_t BH = (size_t)256 * 512;
  unsigned* rbBase = bar + (rb << 11);             // 8KB per rb group
  const int fragbase = kh << 6;                    // kh0: 0..63, kh1: 64..127

  for (int t = 0; t <= 256; ++t) {
    const int s = t - layer;
    if (s >= 0 && s < 256) {
      const int cur = s & 1;
      const unsigned* hPrev = (layer ? h1P : h0P) + (size_t)cur * BH;
      unsigned* hOut = (layer ? h1P : h0P) + (size_t)(cur ^ 1) * BH;

      f32x4 acc[4] = {}, accL[4] = {};

      #define MMQ(FRAG, AHI, ALO)                                             \
        {                                                                     \
          const int fb_ = (FRAG) << 10;                                       \
          const int xm_ = ((FRAG) & 7) << 4;                                  \
          _Pragma("unroll")                                                   \
          for (int cf = 0; cf < 4; ++cf) {                                    \
            const int byo_ = fb_ + ((((cf << 8) | (j << 4))) ^ xm_);          \
            s16x8 b_ = *reinterpret_cast<const s16x8*>(bsw + byo_);           \
            acc[cf] = __builtin_amdgcn_mfma_f32_16x16x32_bf16(                \
                __builtin_bit_cast(bf16x8, AHI),                              \
                __builtin_bit_cast(bf16x8, b_), acc[cf], 0, 0, 0);            \
            accL[cf] = __builtin_amdgcn_mfma_f32_16x16x32_bf16(               \
                __builtin_bit_cast(bf16x8, ALO),                              \
                __builtin_bit_cast(bf16x8, b_), accL[cf], 0, 0, 0);           \
          }                                                                   \
        }

      // A source (all plain cacheable loads; coherence via per-step fence):
      //  kh0/layer0 -> packed seq, time-major [s][row][·]
      //  kh0/layer1 -> h0 output of layer0 step s
      //  kh1        -> own layer's previous h
      const unsigned* ap;
      if (kh == 0 && layer == 0) {
        ap = seqP + (size_t)s * 131072 + (size_t)rowg * 512 + koff;
      } else if (kh == 0) {
        ap = h0P + (size_t)(cur ^ 1) * BH + (size_t)rowg * 512 + koff;
      } else {
        ap = hPrev + (size_t)rowg * 512 + koff;
      }
      #pragma unroll
      for (int blk = 0; blk < 2; ++blk) {
        uint4 R0[8], R1[8];
        #pragma unroll
        for (int q = 0; q < 8; ++q) {
          const unsigned* p = ap + (((blk << 3) | q) << 5);
          R0[q] = *reinterpret_cast<const uint4*>(p);
          R1[q] = *reinterpret_cast<const uint4*>(p + 4);
        }
        #pragma unroll
        for (int q = 0; q < 8; ++q) {
          s16x8 ahi, alo;
          unpack_pk(R0[q], R1[q], ahi, alo);
          MMQ((fragbase + ((((blk << 3) | q) << 2) | g)), ahi, alo)
        }
      }
      #undef MMQ

      // ---- kh1: deposit partials; kh0: finish cell after sync ----
      if (kh == 1) {
        #pragma unroll
        for (int r = 0; r < 4; ++r) {
          const int lrow = ws * 16 + (g << 2) + r;
          f32x4 v = {acc[0][r] + accL[0][r], acc[1][r] + accL[1][r],
                     acc[2][r] + accL[2][r], acc[3][r] + accL[3][r]};
          *reinterpret_cast<f32x4*>(bsw + REDOFF + lrow * 256 + j * 16) = v;
        }
      }
      __syncthreads();
      if (kh == 0) {
        #pragma unroll
        for (int r = 0; r < 4; ++r) {
          const int lrow = ws * 16 + (g << 2) + r;
          f32x4 red = *reinterpret_cast<const f32x4*>(bsw + REDOFF + lrow * 256 + j * 16);
          const int row = rbase + r;
          float zi = acc[0][r] + accL[0][r] + red[0] + bi;
          float zf = acc[1][r] + accL[1][r] + red[1] + bff;
          float zg = acc[2][r] + accL[2][r] + red[2] + bg;
          float zo = acc[3][r] + accL[3][r] + red[3] + bo;
          float cn = sigf(zf) * creg[r] + sigf(zi) * tanhf(zg);
          float hn = sigf(zo) * tanhf(cn);
          if (s >= msl[r]) { cn = creg[r]; hn = hreg[r]; }   // masked: carry
          creg[r] = cn; hreg[r] = hn;
          short hh, hl; split2(hn, hh, hl);
          unsigned pk = ((unsigned)(unsigned short)hl << 16)
                      | (unsigned)(unsigned short)hh;
          __hip_atomic_store(&hOut[(size_t)row * 512 + u], pk,
                             __ATOMIC_RELAXED, __HIP_MEMORY_SCOPE_AGENT);
        }
      }
    }
    if (t < 256) barrier_rb(rbBase, wgLocal, (unsigned)(t + 1));
  }
}

// ---------------------------------------------------------------------------
// Head GEMM: 64x64 tile, B (bf16 hi) from global, packed A, 2-term MFMA.
// EPI 1 = relu6 -> packed hi|lo; EPI 2 = f32 out.
// ---------------------------------------------------------------------------
template<int EPI>
__global__ __launch_bounds__(256) void head_gemm(
    const unsigned* __restrict__ a0, int sA0,
    const unsigned* __restrict__ a1, int sA1, int kSplit,
    const short* __restrict__ Wh, const float* __restrict__ bias,
    int N, int K,
    unsigned* __restrict__ outP, float* __restrict__ outf)
{
  const int cb = blockIdx.x, rb = blockIdx.y;     // e == rb
  const int tid = threadIdx.x, wave = tid >> 6, lane = tid & 63;
  const int j = lane & 15;
  const int rowg = rb * 64 + wave * 16 + j;
  const int koff = (lane >> 4) << 3;
  const short* We = Wh + ((size_t)rb * N + cb * 64) * K;
  f32x4 acc[4] = {}, accL[4] = {};
  for (int ks = 0; ks < (K >> 5); ++ks) {
    const int kl = (ks << 5) + koff;
    const unsigned* ap = (kl < kSplit)
        ? (a0 + (size_t)rowg * sA0 + kl)
        : (a1 + (size_t)rowg * sA1 + (kl - kSplit));
    uint4 q0 = *reinterpret_cast<const uint4*>(ap);
    uint4 q1 = *reinterpret_cast<const uint4*>(ap + 4);
    s16x8 ahi, alo; unpack_pk(q0, q1, ahi, alo);
    #pragma unroll
    for (int cf = 0; cf < 4; ++cf) {
      const int ccol = (cf << 4) + j;
      s16x8 b = *reinterpret_cast<const s16x8*>(We + (size_t)ccol * K + kl);
      acc[cf] = __builtin_amdgcn_mfma_f32_16x16x32_bf16(
          __builtin_bit_cast(bf16x8, ahi), __builtin_bit_cast(bf16x8, b),
          acc[cf], 0, 0, 0);
      accL[cf] = __builtin_amdgcn_mfma_f32_16x16x32_bf16(
          __builtin_bit_cast(bf16x8, alo), __builtin_bit_cast(bf16x8, b),
          accL[cf], 0, 0, 0);
    }
  }
  const int rbase = rb * 64 + wave * 16 + ((lane >> 4) << 2);
  #pragma unroll
  for (int cf = 0; cf < 4; ++cf) {
    const int col = cb * 64 + cf * 16 + j;
    const float bb = bias[(size_t)rb * N + col];
    #pragma unroll
    for (int r = 0; r < 4; ++r) {
      float z = acc[cf][r] + accL[cf][r] + bb;
      if (EPI == 1) {
        z = fminf(fmaxf(z, 0.f), 6.f);
        short hh, hl; split2(z, hh, hl);
        outP[(size_t)(rbase + r) * N + col] =
            ((unsigned)(unsigned short)hl << 16) | (unsigned)(unsigned short)hh;
      } else {
        outf[(size_t)(rbase + r) * N + col] = z;
      }
    }
  }
}

// ---------------------------------------------------------------------------
// Prep kernels.
// ---------------------------------------------------------------------------
__global__ __launch_bounds__(256) void fold_lstm(
    const float* __restrict__ W, const float* __restrict__ U,
    const float* __restrict__ al, const float* __restrict__ ral,
    const float* __restrict__ ga, const float* __restrict__ rga,
    short* __restrict__ Wf)
{
  __shared__ float T[64][65];
  const int tid = threadIdx.x;
  const int kb = blockIdx.x * 64;
  const int cb = blockIdx.y;
  const int le = blockIdx.z;
  const int l  = le >> 2;
  const int kl = tid >> 2;
  const int g  = tid & 3;
  const int k  = kb + kl;
  const bool isW = k < 512;
  const int kk = isW ? k : k - 512;
  const float* src = (isW ? W : U) + ((size_t)l * 512 + kk) * 2048;
  const float  a   = (isW ? al : ral)[(size_t)le * 512 + kk];
  const float* gam = (isW ? ga : rga) + (size_t)le * 2048;
  const int colBase = g * 512 + cb * 16;
  const float4* s4 = reinterpret_cast<const float4*>(src + colBase);
  const float4* g4 = reinterpret_cast<const float4*>(gam + colBase);
  #pragma unroll
  for (int q = 0; q < 4; ++q) {
    float4 v = s4[q], gv = g4[q];
    T[kl][g * 16 + q * 4 + 0] = v.x * a * gv.x;
    T[kl][g * 16 + q * 4 + 1] = v.y * a * gv.y;
    T[kl][g * 16 + q * 4 + 2] = v.z * a * gv.z;
    T[kl][g * 16 + q * 4 + 3] = v.w * a * gv.w;
  }
  __syncthreads();
  const int cl = tid >> 2, kq0 = (tid & 3) * 16;
  alignas(16) short tH[16];
  #pragma unroll
  for (int q = 0; q < 16; ++q) tH[q] = f2bfs(T[kq0 + q][cl]);
  size_t dst = ((size_t)le * 2048 + cb * 64 + cl) * 1024 + kb + kq0;
  *reinterpret_cast<s16x8*>(Wf + dst)     = *reinterpret_cast<s16x8*>(tH);
  *reinterpret_cast<s16x8*>(Wf + dst + 8) = *reinterpret_cast<s16x8*>(tH + 8);
}

__global__ __launch_bounds__(256) void fold_plain(
    const float* __restrict__ src, const float* __restrict__ al,
    const float* __restrict__ ga, short* __restrict__ dst, int N, int K)
{
  __shared__ float T[64][65];
  const int tid = threadIdx.x;
  const int kb = blockIdx.x * 64;
  const int nb = blockIdx.y;
  const int e  = blockIdx.z;
  const int kl = tid >> 2;
  const int c0 = (tid & 3) * 16;
  const int k  = kb + kl;
  const float a = al[(size_t)e * K + k];
  const int colBase = nb * 64 + c0;
  const float4* s4 = reinterpret_cast<const float4*>(src + (size_t)k * N + colBase);
  const float4* g4 = reinterpret_cast<const float4*>(ga + (size_t)e * N + colBase);
  #pragma unroll
  for (int q = 0; q < 4; ++q) {
    float4 v = s4[q], gv = g4[q];
    T[kl][c0 + q * 4 + 0] = v.x * a * gv.x;
    T[kl][c0 + q * 4 + 1] = v.y * a * gv.y;
    T[kl][c0 + q * 4 + 2] = v.z * a * gv.z;
    T[kl][c0 + q * 4 + 3] = v.w * a * gv.w;
  }
  __syncthreads();
  const int cl = tid >> 2, kq0 = (tid & 3) * 16;
  alignas(16) short tH[16];
  #pragma unroll
  for (int q = 0; q < 16; ++q) tH[q] = f2bfs(T[kq0 + q][cl]);
  size_t d = ((size_t)e * N + nb * 64 + cl) * K + kb + kq0;
  *reinterpret_cast<s16x8*>(dst + d)     = *reinterpret_cast<s16x8*>(tH);
  *reinterpret_cast<s16x8*>(dst + d + 8) = *reinterpret_cast<s16x8*>(tH + 8);
}

__global__ void fold_bias_lstm(const float* __restrict__ b, float* __restrict__ bf) {
  int idx = blockIdx.x * 256 + threadIdx.x;          // 16384
  int cp = idx & 2047, le = idx >> 11;
  int ublk = cp >> 6, g = (cp >> 4) & 3, jj = cp & 15;
  bf[idx] = b[(size_t)le * 2048 + g * 512 + ublk * 16 + jj];
}

__global__ void cvt_pack(const float* __restrict__ s,
                         unsigned* __restrict__ d, int n) {
  int i = blockIdx.x * blockDim.x + threadIdx.x;
  if (i < n) {
    short h, l; split2(s[i], h, l);
    d[i] = ((unsigned)(unsigned short)l << 16) | (unsigned)(unsigned short)h;
  }
}

// seq [row][t][512] fp32 -> packed (lo|hi) u32, TIME-MAJOR [t][row][512]
__global__ __launch_bounds__(128) void pack_seq(const float* __restrict__ s,
                                                unsigned* __restrict__ d) {
  const int t = blockIdx.x;        // 256
  const int row = blockIdx.y;      // 256
  const int d0 = threadIdx.x * 4;  // 128 threads x 4 elems
  float4 v = *reinterpret_cast<const float4*>(
      s + ((size_t)row * 256 + t) * 512 + d0);
  uint4 o; short h, l;
  split2(v.x, h, l); o.x = ((unsigned)(unsigned short)l << 16) | (unsigned)(unsigned short)h;
  split2(v.y, h, l); o.y = ((unsigned)(unsigned short)l << 16) | (unsigned)(unsigned short)h;
  split2(v.z, h, l); o.z = ((unsigned)(unsigned short)l << 16) | (unsigned)(unsigned short)h;
  split2(v.w, h, l); o.w = ((unsigned)(unsigned short)l << 16) | (unsigned)(unsigned short)h;
  *reinterpret_cast<uint4*>(d + ((size_t)t * 256 + row) * 512 + d0) = o;
}

__global__ void zero_ws(float4* p, int n) {
  int i = blockIdx.x * blockDim.x + threadIdx.x;
  if (i < n) p[i] = make_float4(0.f, 0.f, 0.f, 0.f);
}

__global__ void init_bar(unsigned* bar) {
  int i = blockIdx.x * 256 + threadIdx.x;
  if (i < 8192) bar[i] = 0u;
}

// ---------------------------------------------------------------------------
// workspace layout (bytes)
// ---------------------------------------------------------------------------
constexpr size_t OFF_WF    = 0;                      // 2*4*2048*1024*2 = 33554432
constexpr size_t OFF_WHID  = 33554432;               // 4*256*768*2     = 1572864
constexpr size_t OFF_WOUT  = OFF_WHID + 1572864;     // 4*64*256*2      = 131072
constexpr size_t OFF_BIASF = OFF_WOUT + 131072;      // 16384*4         = 65536
constexpr size_t OFF_CTXP  = OFF_BIASF + 65536;      // 65536*4         = 262144
constexpr size_t OFF_H0P   = OFF_CTXP + 262144;      // 2*256*512*4     = 1048576
constexpr size_t OFF_H1P   = OFF_H0P + 1048576;      // 1048576
constexpr size_t OFF_HIDP  = OFF_H1P + 1048576;      // 256*256*4       = 262144
constexpr size_t OFF_BAR   = OFF_HIDP + 262144;      // 32768 (4 rb x 8KB)
constexpr size_t OFF_SEQP  = OFF_BAR + 32768;        // 33554432*4 = 134217728

extern "C" void kernel_launch(void* const* d_in, const int* in_sizes, int n_in,
                              void* d_out, int out_size, void* d_ws, size_t ws_size,
                              hipStream_t stream) {
  (void)in_sizes; (void)n_in; (void)out_size; (void)ws_size;
  const float* seq  = (const float*)d_in[0];
  const float* ctx  = (const float*)d_in[1];
  const int*   slen = (const int*)d_in[2];
  const float* lW   = (const float*)d_in[3];
  const float* lU   = (const float*)d_in[4];
  const float* lb   = (const float*)d_in[5];
  const float* lal  = (const float*)d_in[6];
  const float* lga  = (const float*)d_in[7];
  const float* lral = (const float*)d_in[8];
  const float* lrga = (const float*)d_in[9];
  const float* hW   = (const float*)d_in[10];
  const float* hb   = (const float*)d_in[11];
  const float* hal  = (const float*)d_in[12];
  const float* hga  = (const float*)d_in[13];
  const float* oW   = (const float*)d_in[14];
  const float* ob   = (const float*)d_in[15];
  const float* oal  = (const float*)d_in[16];
  const float* oga  = (const float*)d_in[17];

  char* ws = (char*)d_ws;
  short*    Wf    = (short*)(ws + OFF_WF);
  short*    Whid  = (short*)(ws + OFF_WHID);
  short*    Wout  = (short*)(ws + OFF_WOUT);
  float*    biasF = (float*)(ws + OFF_BIASF);
  unsigned* ctxP  = (unsigned*)(ws + OFF_CTXP);
  unsigned* h0P   = (unsigned*)(ws + OFF_H0P);
  unsigned* h1P   = (unsigned*)(ws + OFF_H1P);
  unsigned* hidP  = (unsigned*)(ws + OFF_HIDP);
  unsigned* bar   = (unsigned*)(ws + OFF_BAR);
  unsigned* seqP  = (unsigned*)(ws + OFF_SEQP);

  // allow 144 KiB dynamic LDS
  (void)hipFuncSetAttribute(reinterpret_cast<const void*>(lstm_persist),
                            hipFuncAttributeMaxDynamicSharedMemorySize, 147456);

  // prep (every call: deterministic, no caching)
  fold_lstm<<<dim3(16, 32, 8), 256, 0, stream>>>(lW, lU, lal, lral, lga, lrga, Wf);
  fold_plain<<<dim3(12, 4, 4), 256, 0, stream>>>(hW, hal, hga, Whid, 256, 768);
  fold_plain<<<dim3(4, 1, 4), 256, 0, stream>>>(oW, oal, oga, Wout, 64, 256);
  fold_bias_lstm<<<64, 256, 0, stream>>>(lb, biasF);
  cvt_pack<<<256, 256, 0, stream>>>(ctx, ctxP, 65536);
  pack_seq<<<dim3(256, 256), 128, 0, stream>>>(seq, seqP);
  zero_ws<<<512, 256, 0, stream>>>((float4*)(ws + OFF_H0P), 2097152 / 16);
  init_bar<<<32, 256, 0, stream>>>(bar);

  // the whole recurrence in one persistent kernel (256 WGs = 1/CU, 8 waves)
  lstm_persist<<<256, 512, 147456, stream>>>(seqP, h0P, h1P, Wf, biasF, slen, bar);

  // head: hidden = relu6(((h1,ctx)*a)@hid_W*g + b); out = ((hid*a)@out_W*g + b)
  head_gemm<1><<<dim3(4, 4), 256, 0, stream>>>(
      h1P /* final h1 in buf0 */, 512,
      ctxP, 256, 512,
      Whid, hb, 256, 768, hidP, nullptr);
  head_gemm<2><<<dim3(1, 4), 256, 0, stream>>>(
      hidP, 256,
      hidP, 256, 256,
      Wout, ob, 64, 256,
      nullptr, (float*)d_out);
}

// Round 9
// 3079.877 us; speedup vs baseline: 1.8244x; 1.0225x over previous
//
#include <hip/hip_runtime.h>
#include <cstdint>
#include <cstddef>

// Rank1BayesianRNN on MI355X — round 9: decoupled per-layer barriers.
// vs round 8 (13.4us/step): the 64-WG cross-layer lockstep barrier was the
// wall. Now:
//  * per-(layer,rb) 32-WG barrier (XCD-affine group) + progress counters:
//    layer1 gates on P0 >= s+1 (h0[s] ready), layer0 gates on P1 >= t-3
//    (ring-slot reuse). h0 = 4-deep ring; layer0 free-runs 1..3 steps ahead.
//  * all 32 A-loads hoisted per step (one latency hump).
//  * fast tanh (exp-based, clamped).
// Everything else as round 8: time-major packed seq, weights LDS-resident,
// h packed (lo16|hi16) sc1 write-through stores + per-step acquire fence,
// zero-poll tree barrier, A-side fp32 via bf16 hi/lo 2-term MFMA.

typedef __attribute__((ext_vector_type(8))) short  s16x8;
typedef __attribute__((ext_vector_type(8))) __bf16 bf16x8;
typedef __attribute__((ext_vector_type(4))) float  f32x4;
typedef unsigned long long ull;

__device__ __forceinline__ short f2bfs(float f) {
  union { float f; unsigned u; } v; v.f = f;
  unsigned r = v.u + 0x7FFFu + ((v.u >> 16) & 1u);   // RNE
  return (short)(r >> 16);
}
__device__ __forceinline__ float bf2f(short s) {
  union { unsigned u; float f; } v; v.u = ((unsigned)(unsigned short)s) << 16;
  return v.f;
}
__device__ __forceinline__ void split2(float v, short& hi, short& lo) {
  hi = f2bfs(v);
  lo = f2bfs(v - bf2f(hi));
}
__device__ __forceinline__ float sigf(float x) { return 1.0f / (1.0f + __expf(-x)); }
__device__ __forceinline__ float tanhf_fast(float x) {
  float xc = fminf(fmaxf(x, -15.f), 15.f);
  float e = __expf(2.f * xc);
  return __fdividef(e - 1.f, e + 1.f);
}

// pk = (lo16<<16)|hi16. v_perm: sel bytes 0-3 = src1, 4-7 = src0.
__device__ __forceinline__ void unpack_pk(const uint4 r0, const uint4 r1,
                                          s16x8& hi, s16x8& lo) {
  uint4 hv, lv;
  hv.x = __builtin_amdgcn_perm(r0.y, r0.x, 0x05040100u);
  lv.x = __builtin_amdgcn_perm(r0.y, r0.x, 0x07060302u);
  hv.y = __builtin_amdgcn_perm(r0.w, r0.z, 0x05040100u);
  lv.y = __builtin_amdgcn_perm(r0.w, r0.z, 0x07060302u);
  hv.z = __builtin_amdgcn_perm(r1.y, r1.x, 0x05040100u);
  lv.z = __builtin_amdgcn_perm(r1.y, r1.x, 0x07060302u);
  hv.w = __builtin_amdgcn_perm(r1.w, r1.z, 0x05040100u);
  lv.w = __builtin_amdgcn_perm(r1.w, r1.z, 0x07060302u);
  hi = __builtin_bit_cast(s16x8, hv);
  lo = __builtin_bit_cast(s16x8, lv);
}

#define HIP_RLX __ATOMIC_RELAXED
#define HIP_AGT __HIP_MEMORY_SCOPE_AGENT

// Group barrier (32 WGs, 4 cohorts x 8 -> root), publish progress, gate on
// other layer's progress, then ONE agent-acquire fence. All atomics RELAXED;
// h stores are sc1 write-through drained by the leading __syncthreads.
// grpBase u32 layout: cohort c at [c*16], root [64], flag of WG w [128+w*16].
__device__ __forceinline__ void step_sync(unsigned* grpBase, unsigned* Pme,
                                          unsigned* Pother, int cb,
                                          unsigned tstep, int pneed) {
  __syncthreads();                        // drain vmcnt: h stores at L3
  if (threadIdx.x < 64) {                 // wave 0 runs the protocol
    const int lane = threadIdx.x;
    int rel = 0;
    if (lane == 0) {
      unsigned a = __hip_atomic_fetch_add(grpBase + ((cb >> 3) << 4), 1u,
                                          HIP_RLX, HIP_AGT);
      if (a == 8u * tstep - 1u) {         // cohort complete
        unsigned r = __hip_atomic_fetch_add(grpBase + 64, 1u, HIP_RLX, HIP_AGT);
        if (r == 4u * tstep - 1u) rel = 1;    // I am the releaser
      }
    }
    rel = __shfl(rel, 0);
    unsigned* flags = grpBase + 128;
    if (rel) {
      if (lane < 32)
        __hip_atomic_store(flags + lane * 16, tstep, HIP_RLX, HIP_AGT);
      if (lane == 0)
        __hip_atomic_store(Pme, tstep, HIP_RLX, HIP_AGT);
    }
    if (lane == 0) {
      if (!rel) {
        int spins = 0;
        while (__hip_atomic_load(flags + cb * 16, HIP_RLX, HIP_AGT) < tstep) {
          __builtin_amdgcn_s_sleep(1);
          if (++spins > (1 << 24)) break;     // safety: never hang
        }
      }
      if (pneed > 0) {
        int spins = 0;
        while ((int)__hip_atomic_load(Pother, HIP_RLX, HIP_AGT) < pneed) {
          __builtin_amdgcn_s_sleep(1);
          if (++spins > (1 << 24)) break;
        }
      }
      __builtin_amdgcn_fence(__ATOMIC_ACQUIRE, "agent");  // one inv per step
    }
  }
  __syncthreads();
}

// ---------------------------------------------------------------------------
// Persistent LSTM. XCD-affine decode: cls = wg&7 -> (layer = cls>>2, rb =
// cls&3); cb = wg>>3 (0..31). 512 threads = 8 waves: wave = kh*4 + ws;
// kh 0 -> k<512 (+cell epilogue), kh 1 -> k>=512 (+LDS reduce).
// h0 = 4-slot ring (layer0 step t: reads slot t&3, writes slot (t+1)&3;
// layer1 step t reads slot (t+1)&3). h1 = 2-slot ping-pong.
// LDS: 128KB weights (fragment-linear swizzled) + 16KB reduce.
// ---------------------------------------------------------------------------
#define REDOFF 131072
#define BHU 131072      // u32 per h slot (256 rows x 512)

__global__ __launch_bounds__(512, 1) void lstm_persist(
    const unsigned* __restrict__ seqP,     // time-major [t][row][512]
    unsigned* __restrict__ h0P, unsigned* __restrict__ h1P,
    const short* __restrict__ Wf, const float* __restrict__ biasF,
    const int* __restrict__ slen, unsigned* __restrict__ bar)
{
  extern __shared__ __align__(16) char bsw[];
  const int wg = blockIdx.x;
  const int cls = wg & 7;                          // XCD affinity class
  const int layer = cls >> 2;
  const int rb = cls & 3;                          // ensemble e == rb
  const int cb = wg >> 3;                          // 0..31
  const int tid = threadIdx.x;
  const int wave = tid >> 6, lane = tid & 63;
  const int kh = wave >> 2, ws = wave & 3;         // k-half, row-tile

  // ---- stage weight slice into LDS, fragment-linear swizzled ----
  const short* Wfe = Wf + ((size_t)(layer * 4 + rb) * 2048 + cb * 64) * 1024;
  #pragma unroll
  for (int i = 0; i < 16; ++i) {
    int f = (i << 9) + tid;                        // 0..8191 fragments
    int col = f >> 7, fr = f & 127;
    s16x8 v = *reinterpret_cast<const s16x8*>(Wfe + (size_t)col * 1024 + (fr << 3));
    int byo = (fr << 10) + (((col << 4)) ^ ((fr & 7) << 4));
    *reinterpret_cast<s16x8*>(bsw + byo) = v;
  }
  __syncthreads();

  const int j = lane & 15;
  const int g = lane >> 4;
  const int koff = g << 3;
  const int rowg = rb * 64 + ws * 16 + j;          // A row for this lane
  const int rbase = rb * 64 + ws * 16 + (g << 2);  // epilogue rows (kh==0)
  const int u = cb * 16 + j;
  const float* bp = biasF + (size_t)(layer * 4 + rb) * 2048 + cb * 64 + j;
  const float bi = bp[0], bff = bp[16], bg = bp[32], bo = bp[48];
  int msl[4];
  #pragma unroll
  for (int r = 0; r < 4; ++r) msl[r] = slen[rbase + r];

  float creg[4] = {0.f, 0.f, 0.f, 0.f};
  float hreg[4] = {0.f, 0.f, 0.f, 0.f};
  unsigned* grpBase = bar + (cls << 10);           // 4KB per group
  unsigned* Pme     = bar + 8192 + (cls << 4);
  unsigned* Pother  = bar + 8192 + ((cls ^ 4) << 4);
  const int fragbase = kh << 6;                    // kh0: 0..63, kh1: 64..127

  // initial gate: layer1 needs h0[0]; then one fence before first loads.
  if (tid == 0) {
    if (layer == 1) {
      int spins = 0;
      while (__hip_atomic_load(Pother, HIP_RLX, HIP_AGT) < 1u) {
        __builtin_amdgcn_s_sleep(1);
        if (++spins > (1 << 24)) break;
      }
    }
    __builtin_amdgcn_fence(__ATOMIC_ACQUIRE, "agent");
  }
  __syncthreads();

  for (int t = 0; t < 256; ++t) {
    // ---- A source for this step (all plain cacheable loads) ----
    const unsigned* ap;
    if (kh == 0) {
      ap = (layer == 0)
         ? seqP + (size_t)t * 131072 + (size_t)rowg * 512 + koff
         : h0P + (size_t)((t + 1) & 3) * BHU + (size_t)rowg * 512 + koff;
    } else {
      ap = (layer == 0)
         ? h0P + (size_t)(t & 3) * BHU + (size_t)rowg * 512 + koff
         : h1P + (size_t)(t & 1) * BHU + (size_t)rowg * 512 + koff;
    }

    // hoist all 32 loads (one latency hump)
    uint4 R0[16], R1[16];
    #pragma unroll
    for (int q = 0; q < 16; ++q) {
      R0[q] = *reinterpret_cast<const uint4*>(ap + (q << 5));
      R1[q] = *reinterpret_cast<const uint4*>(ap + (q << 5) + 4);
    }

    f32x4 acc[4] = {}, accL[4] = {};
    #pragma unroll
    for (int q = 0; q < 16; ++q) {
      s16x8 ahi, alo;
      unpack_pk(R0[q], R1[q], ahi, alo);
      const int frag = fragbase + ((q << 2) | g);
      const int fb_ = frag << 10;
      const int xm_ = (frag & 7) << 4;
      #pragma unroll
      for (int cf = 0; cf < 4; ++cf) {
        const int byo_ = fb_ + ((((cf << 8) | (j << 4))) ^ xm_);
        s16x8 b_ = *reinterpret_cast<const s16x8*>(bsw + byo_);
        acc[cf] = __builtin_amdgcn_mfma_f32_16x16x32_bf16(
            __builtin_bit_cast(bf16x8, ahi), __builtin_bit_cast(bf16x8, b_),
            acc[cf], 0, 0, 0);
        accL[cf] = __builtin_amdgcn_mfma_f32_16x16x32_bf16(
            __builtin_bit_cast(bf16x8, alo), __builtin_bit_cast(bf16x8, b_),
            accL[cf], 0, 0, 0);
      }
    }

    // ---- kh1: deposit partials; kh0: finish cell after sync ----
    if (kh == 1) {
      #pragma unroll
      for (int r = 0; r < 4; ++r) {
        const int lrow = ws * 16 + (g << 2) + r;
        f32x4 v = {acc[0][r] + accL[0][r], acc[1][r] + accL[1][r],
                   acc[2][r] + accL[2][r], acc[3][r] + accL[3][r]};
        *reinterpret_cast<f32x4*>(bsw + REDOFF + lrow * 256 + j * 16) = v;
      }
    }
    __syncthreads();
    if (kh == 0) {
      unsigned* hOut = (layer == 0)
          ? h0P + (size_t)((t + 1) & 3) * BHU
          : h1P + (size_t)((t & 1) ^ 1) * BHU;
      #pragma unroll
      for (int r = 0; r < 4; ++r) {
        const int lrow = ws * 16 + (g << 2) + r;
        f32x4 red = *reinterpret_cast<const f32x4*>(bsw + REDOFF + lrow * 256 + j * 16);
        const int row = rbase + r;
        float zi = acc[0][r] + accL[0][r] + red[0] + bi;
        float zf = acc[1][r] + accL[1][r] + red[1] + bff;
        float zg = acc[2][r] + accL[2][r] + red[2] + bg;
        float zo = acc[3][r] + accL[3][r] + red[3] + bo;
        float cn = sigf(zf) * creg[r] + sigf(zi) * tanhf_fast(zg);
        float hn = sigf(zo) * tanhf_fast(cn);
        if (t >= msl[r]) { cn = creg[r]; hn = hreg[r]; }   // masked: carry
        creg[r] = cn; hreg[r] = hn;
        short hh, hl; split2(hn, hh, hl);
        unsigned pk = ((unsigned)(unsigned short)hl << 16)
                    | (unsigned)(unsigned short)hh;
        __hip_atomic_store(&hOut[(size_t)row * 512 + u], pk, HIP_RLX, HIP_AGT);
      }
    }

    // barrier + publish P=t+1 + gate next step + fence.
    // layer0 next step t+1 overwrites h0[t-2] -> needs P1 >= t-2.
    // layer1 next step t+1 reads h0[t+1]      -> needs P0 >= t+2.
    int pneed = (t < 255) ? (layer == 0 ? t - 2 : t + 2) : 0;
    step_sync(grpBase, Pme, Pother, cb, (unsigned)(t + 1), pneed);
  }
}

// ---------------------------------------------------------------------------
// Head GEMM: 64x64 tile, B (bf16 hi) from global, packed A, 2-term MFMA.
// EPI 1 = relu6 -> packed hi|lo; EPI 2 = f32 out.
// ---------------------------------------------------------------------------
template<int EPI>
__global__ __launch_bounds__(256) void head_gemm(
    const unsigned* __restrict__ a0, int sA0,
    const unsigned* __restrict__ a1, int sA1, int kSplit,
    const short* __restrict__ Wh, const float* __restrict__ bias,
    int N, int K,
    unsigned* __restrict__ outP, float* __restrict__ outf)
{
  const int cb = blockIdx.x, rb = blockIdx.y;     // e == rb
  const int tid = threadIdx.x, wave = tid >> 6, lane = tid & 63;
  const int j = lane & 15;
  const int rowg = rb * 64 + wave * 16 + j;
  const int koff = (lane >> 4) << 3;
  const short* We = Wh + ((size_t)rb * N + cb * 64) * K;
  f32x4 acc[4] = {}, accL[4] = {};
  for (int ks = 0; ks < (K >> 5); ++ks) {
    const int kl = (ks << 5) + koff;
    const unsigned* ap = (kl < kSplit)
        ? (a0 + (size_t)rowg * sA0 + kl)
        : (a1 + (size_t)rowg * sA1 + (kl - kSplit));
    uint4 q0 = *reinterpret_cast<const uint4*>(ap);
    uint4 q1 = *reinterpret_cast<const uint4*>(ap + 4);
    s16x8 ahi, alo; unpack_pk(q0, q1, ahi, alo);
    #pragma unroll
    for (int cf = 0; cf < 4; ++cf) {
      const int ccol = (cf << 4) + j;
      s16x8 b = *reinterpret_cast<const s16x8*>(We + (size_t)ccol * K + kl);
      acc[cf] = __builtin_amdgcn_mfma_f32_16x16x32_bf16(
          __builtin_bit_cast(bf16x8, ahi), __builtin_bit_cast(bf16x8, b),
          acc[cf], 0, 0, 0);
      accL[cf] = __builtin_amdgcn_mfma_f32_16x16x32_bf16(
          __builtin_bit_cast(bf16x8, alo), __builtin_bit_cast(bf16x8, b),
          accL[cf], 0, 0, 0);
    }
  }
  const int rbase = rb * 64 + wave * 16 + ((lane >> 4) << 2);
  #pragma unroll
  for (int cf = 0; cf < 4; ++cf) {
    const int col = cb * 64 + cf * 16 + j;
    const float bb = bias[(size_t)rb * N + col];
    #pragma unroll
    for (int r = 0; r < 4; ++r) {
      float z = acc[cf][r] + accL[cf][r] + bb;
      if (EPI == 1) {
        z = fminf(fmaxf(z, 0.f), 6.f);
        short hh, hl; split2(z, hh, hl);
        outP[(size_t)(rbase + r) * N + col] =
            ((unsigned)(unsigned short)hl << 16) | (unsigned)(unsigned short)hh;
      } else {
        outf[(size_t)(rbase + r) * N + col] = z;
      }
    }
  }
}

// ---------------------------------------------------------------------------
// Prep kernels.
// ---------------------------------------------------------------------------
__global__ __launch_bounds__(256) void fold_lstm(
    const float* __restrict__ W, const float* __restrict__ U,
    const float* __restrict__ al, const float* __restrict__ ral,
    const float* __restrict__ ga, const float* __restrict__ rga,
    short* __restrict__ Wf)
{
  __shared__ float T[64][65];
  const int tid = threadIdx.x;
  const int kb = blockIdx.x * 64;
  const int cb = blockIdx.y;
  const int le = blockIdx.z;
  const int l  = le >> 2;
  const int kl = tid >> 2;
  const int g  = tid & 3;
  const int k  = kb + kl;
  const bool isW = k < 512;
  const int kk = isW ? k : k - 512;
  const float* src = (isW ? W : U) + ((size_t)l * 512 + kk) * 2048;
  const float  a   = (isW ? al : ral)[(size_t)le * 512 + kk];
  const float* gam = (isW ? ga : rga) + (size_t)le * 2048;
  const int colBase = g * 512 + cb * 16;
  const float4* s4 = reinterpret_cast<const float4*>(src + colBase);
  const float4* g4 = reinterpret_cast<const float4*>(gam + colBase);
  #pragma unroll
  for (int q = 0; q < 4; ++q) {
    float4 v = s4[q], gv = g4[q];
    T[kl][g * 16 + q * 4 + 0] = v.x * a * gv.x;
    T[kl][g * 16 + q * 4 + 1] = v.y * a * gv.y;
    T[kl][g * 16 + q * 4 + 2] = v.z * a * gv.z;
    T[kl][g * 16 + q * 4 + 3] = v.w * a * gv.w;
  }
  __syncthreads();
  const int cl = tid >> 2, kq0 = (tid & 3) * 16;
  alignas(16) short tH[16];
  #pragma unroll
  for (int q = 0; q < 16; ++q) tH[q] = f2bfs(T[kq0 + q][cl]);
  size_t dst = ((size_t)le * 2048 + cb * 64 + cl) * 1024 + kb + kq0;
  *reinterpret_cast<s16x8*>(Wf + dst)     = *reinterpret_cast<s16x8*>(tH);
  *reinterpret_cast<s16x8*>(Wf + dst + 8) = *reinterpret_cast<s16x8*>(tH + 8);
}

__global__ __launch_bounds__(256) void fold_plain(
    const float* __restrict__ src, const float* __restrict__ al,
    const float* __restrict__ ga, short* __restrict__ dst, int N, int K)
{
  __shared__ float T[64][65];
  const int tid = threadIdx.x;
  const int kb = blockIdx.x * 64;
  const int nb = blockIdx.y;
  const int e  = blockIdx.z;
  const int kl = tid >> 2;
  const int c0 = (tid & 3) * 16;
  const int k  = kb + kl;
  const float a = al[(size_t)e * K + k];
  const int colBase = nb * 64 + c0;
  const float4* s4 = reinterpret_cast<const float4*>(src + (size_t)k * N + colBase);
  const float4* g4 = reinterpret_cast<const float4*>(ga + (size_t)e * N + colBase);
  #pragma unroll
  for (int q = 0; q < 4; ++q) {
    float4 v = s4[q], gv = g4[q];
    T[kl][c0 + q * 4 + 0] = v.x * a * gv.x;
    T[kl][c0 + q * 4 + 1] = v.y * a * gv.y;
    T[kl][c0 + q * 4 + 2] = v.z * a * gv.z;
    T[kl][c0 + q * 4 + 3] = v.w * a * gv.w;
  }
  __syncthreads();
  const int cl = tid >> 2, kq0 = (tid & 3) * 16;
  alignas(16) short tH[16];
  #pragma unroll
  for (int q = 0; q < 16; ++q) tH[q] = f2bfs(T[kq0 + q][cl]);
  size_t d = ((size_t)e * N + nb * 64 + cl) * K + kb + kq0;
  *reinterpret_cast<s16x8*>(dst + d)     = *reinterpret_cast<s16x8*>(tH);
  *reinterpret_cast<s16x8*>(dst + d + 8) = *reinterpret_cast<s16x8*>(tH + 8);
}

__global__ void fold_bias_lstm(const float* __restrict__ b, float* __restrict__ bf) {
  int idx = blockIdx.x * 256 + threadIdx.x;          // 16384
  int cp = idx & 2047, le = idx >> 11;
  int ublk = cp >> 6, g = (cp >> 4) & 3, jj = cp & 15;
  bf[idx] = b[(size_t)le * 2048 + g * 512 + ublk * 16 + jj];
}

__global__ void cvt_pack(const float* __restrict__ s,
                         unsigned* __restrict__ d, int n) {
  int i = blockIdx.x * blockDim.x + threadIdx.x;
  if (i < n) {
    short h, l; split2(s[i], h, l);
    d[i] = ((unsigned)(unsigned short)l << 16) | (unsigned)(unsigned short)h;
  }
}

// seq [row][t][512] fp32 -> packed (lo|hi) u32, TIME-MAJOR [t][row][512]
__global__ __launch_bounds__(128) void pack_seq(const float* __restrict__ s,
                                                unsigned* __restrict__ d) {
  const int t = blockIdx.x;        // 256
  const int row = blockIdx.y;      // 256
  const int d0 = threadIdx.x * 4;  // 128 threads x 4 elems
  float4 v = *reinterpret_cast<const float4*>(
      s + ((size_t)row * 256 + t) * 512 + d0);
  uint4 o; short h, l;
  split2(v.x, h, l); o.x = ((unsigned)(unsigned short)l << 16) | (unsigned)(unsigned short)h;
  split2(v.y, h, l); o.y = ((unsigned)(unsigned short)l << 16) | (unsigned)(unsigned short)h;
  split2(v.z, h, l); o.z = ((unsigned)(unsigned short)l << 16) | (unsigned)(unsigned short)h;
  split2(v.w, h, l); o.w = ((unsigned)(unsigned short)l << 16) | (unsigned)(unsigned short)h;
  *reinterpret_cast<uint4*>(d + ((size_t)t * 256 + row) * 512 + d0) = o;
}

__global__ void zero_ws(float4* p, int n) {
  int i = blockIdx.x * blockDim.x + threadIdx.x;
  if (i < n) p[i] = make_float4(0.f, 0.f, 0.f, 0.f);
}

__global__ void init_bar(unsigned* bar) {
  int i = blockIdx.x * 256 + threadIdx.x;
  if (i < 16384) bar[i] = 0u;
}

// ---------------------------------------------------------------------------
// workspace layout (bytes)
// ---------------------------------------------------------------------------
constexpr size_t OFF_WF    = 0;                      // 2*4*2048*1024*2 = 33554432
constexpr size_t OFF_WHID  = 33554432;               // 4*256*768*2     = 1572864
constexpr size_t OFF_WOUT  = OFF_WHID + 1572864;     // 4*64*256*2      = 131072
constexpr size_t OFF_BIASF = OFF_WOUT + 131072;      // 16384*4         = 65536
constexpr size_t OFF_CTXP  = OFF_BIASF + 65536;      // 65536*4         = 262144
constexpr size_t OFF_H0P   = OFF_CTXP + 262144;      // 4*256*512*4     = 2097152
constexpr size_t OFF_H1P   = OFF_H0P + 2097152;      // 2*256*512*4     = 1048576
constexpr size_t OFF_HIDP  = OFF_H1P + 1048576;      // 256*256*4       = 262144
constexpr size_t OFF_BAR   = OFF_HIDP + 262144;      // 65536
constexpr size_t OFF_SEQP  = OFF_BAR + 65536;        // 33554432*4 = 134217728

extern "C" void kernel_launch(void* const* d_in, const int* in_sizes, int n_in,
                              void* d_out, int out_size, void* d_ws, size_t ws_size,
                              hipStream_t stream) {
  (void)in_sizes; (void)n_in; (void)out_size; (void)ws_size;
  const float* seq  = (const float*)d_in[0];
  const float* ctx  = (const float*)d_in[1];
  const int*   slen = (const int*)d_in[2];
  const float* lW   = (const float*)d_in[3];
  const float* lU   = (const float*)d_in[4];
  const float* lb   = (const float*)d_in[5];
  const float* lal  = (const float*)d_in[6];
  const float* lga  = (const float*)d_in[7];
  const float* lral = (const float*)d_in[8];
  const float* lrga = (const float*)d_in[9];
  const float* hW   = (const float*)d_in[10];
  const float* hb   = (const float*)d_in[11];
  const float* hal  = (const float*)d_in[12];
  const float* hga  = (const float*)d_in[13];
  const float* oW   = (const float*)d_in[14];
  const float* ob   = (const float*)d_in[15];
  const float* oal  = (const float*)d_in[16];
  const float* oga  = (const float*)d_in[17];

  char* ws = (char*)d_ws;
  short*    Wf    = (short*)(ws + OFF_WF);
  short*    Whid  = (short*)(ws + OFF_WHID);
  short*    Wout  = (short*)(ws + OFF_WOUT);
  float*    biasF = (float*)(ws + OFF_BIASF);
  unsigned* ctxP  = (unsigned*)(ws + OFF_CTXP);
  unsigned* h0P   = (unsigned*)(ws + OFF_H0P);
  unsigned* h1P   = (unsigned*)(ws + OFF_H1P);
  unsigned* hidP  = (unsigned*)(ws + OFF_HIDP);
  unsigned* bar   = (unsigned*)(ws + OFF_BAR);
  unsigned* seqP  = (unsigned*)(ws + OFF_SEQP);

  // allow 144 KiB dynamic LDS
  (void)hipFuncSetAttribute(reinterpret_cast<const void*>(lstm_persist),
                            hipFuncAttributeMaxDynamicSharedMemorySize, 147456);

  // prep (every call: deterministic, no caching)
  fold_lstm<<<dim3(16, 32, 8), 256, 0, stream>>>(lW, lU, lal, lral, lga, lrga, Wf);
  fold_plain<<<dim3(12, 4, 4), 256, 0, stream>>>(hW, hal, hga, Whid, 256, 768);
  fold_plain<<<dim3(4, 1, 4), 256, 0, stream>>>(oW, oal, oga, Wout, 64, 256);
  fold_bias_lstm<<<64, 256, 0, stream>>>(lb, biasF);
  cvt_pack<<<256, 256, 0, stream>>>(ctx, ctxP, 65536);
  pack_seq<<<dim3(256, 256), 128, 0, stream>>>(seq, seqP);
  zero_ws<<<768, 256, 0, stream>>>((float4*)(ws + OFF_H0P), 3145728 / 16);
  init_bar<<<64, 256, 0, stream>>>(bar);

  // the whole recurrence in one persistent kernel (256 WGs = 1/CU, 8 waves)
  lstm_persist<<<256, 512, 147456, stream>>>(seqP, h0P, h1P, Wf, biasF, slen, bar);

  // head: hidden = relu6(((h1,ctx)*a)@hid_W*g + b); out = ((hid*a)@out_W*g + b)
  head_gemm<1><<<dim3(4, 4), 256, 0, stream>>>(
      h1P /* final h1 in slot 0 */, 512,
      ctxP, 256, 512,
      Whid, hb, 256, 768, hidP, nullptr);
  head_gemm<2><<<dim3(1, 4), 256, 0, stream>>>(
      hidP, 256,
      hidP, 256, 256,
      Wout, ob, 64, 256,
      nullptr, (float*)d_out);
}

// Round 10
// 2751.978 us; speedup vs baseline: 2.0418x; 1.1192x over previous
//
#include <hip/hip_runtime.h>
#include <cstdint>
#include <cstddef>

// Rank1BayesianRNN on MI355X — round 10: h exchanged as bf16-hi only.
// vs round 9 (13.3us/step): halve the h-path everywhere.
//  * h state = bf16 hi only, PAIR-PACKED (units 2i,2i+1 in one u32 via
//    __shfl_xor): h loads are direct s16x8 (no unpack), h MFMAs halve,
//    h stores halve. seq keeps hi/lo (layer-0 accuracy).
//  * flattened group barrier: one 32-arriver counter + per-WG flags
//    (one coherence RT less than the 2-level tree).
//  * ctx / hidden / head GEMMs hi-only (single-term MFMA).
// Numerics: weights bf16-hi folded, seq fp32 via bf16 hi/lo 2-term MFMA,
// c fp32 in registers, h bf16. Expected absmax ~0.010-0.015 (thr 0.037).

typedef __attribute__((ext_vector_type(8))) short  s16x8;
typedef __attribute__((ext_vector_type(8))) __bf16 bf16x8;
typedef __attribute__((ext_vector_type(4))) float  f32x4;

__device__ __forceinline__ short f2bfs(float f) {
  union { float f; unsigned u; } v; v.f = f;
  unsigned r = v.u + 0x7FFFu + ((v.u >> 16) & 1u);   // RNE
  return (short)(r >> 16);
}
__device__ __forceinline__ float bf2f(short s) {
  union { unsigned u; float f; } v; v.u = ((unsigned)(unsigned short)s) << 16;
  return v.f;
}
__device__ __forceinline__ void split2(float v, short& hi, short& lo) {
  hi = f2bfs(v);
  lo = f2bfs(v - bf2f(hi));
}
__device__ __forceinline__ float sigf(float x) { return 1.0f / (1.0f + __expf(-x)); }
__device__ __forceinline__ float tanhf_fast(float x) {
  float xc = fminf(fmaxf(x, -15.f), 15.f);
  float e = __expf(2.f * xc);
  return __fdividef(e - 1.f, e + 1.f);
}

// seq pk = (lo16<<16)|hi16. v_perm: sel bytes 0-3 = src1, 4-7 = src0.
__device__ __forceinline__ void unpack_pk(const uint4 r0, const uint4 r1,
                                          s16x8& hi, s16x8& lo) {
  uint4 hv, lv;
  hv.x = __builtin_amdgcn_perm(r0.y, r0.x, 0x05040100u);
  lv.x = __builtin_amdgcn_perm(r0.y, r0.x, 0x07060302u);
  hv.y = __builtin_amdgcn_perm(r0.w, r0.z, 0x05040100u);
  lv.y = __builtin_amdgcn_perm(r0.w, r0.z, 0x07060302u);
  hv.z = __builtin_amdgcn_perm(r1.y, r1.x, 0x05040100u);
  lv.z = __builtin_amdgcn_perm(r1.y, r1.x, 0x07060302u);
  hv.w = __builtin_amdgcn_perm(r1.w, r1.z, 0x05040100u);
  lv.w = __builtin_amdgcn_perm(r1.w, r1.z, 0x07060302u);
  hi = __builtin_bit_cast(s16x8, hv);
  lo = __builtin_bit_cast(s16x8, lv);
}

#define HIP_RLX __ATOMIC_RELAXED
#define HIP_AGT __HIP_MEMORY_SCOPE_AGENT

// Flat group barrier (32 WGs): one counter [0], per-WG flags [128+w*16].
// Arrive RELAXED; last arriver (from its own fetch_add return) releases all
// 32 flags with one wave store + publishes progress; everyone then gates on
// the other layer's progress and does ONE agent-acquire fence.
__device__ __forceinline__ void step_sync(unsigned* grpBase, unsigned* Pme,
                                          unsigned* Pother, int cb,
                                          unsigned tstep, int pneed) {
  __syncthreads();                        // drain vmcnt: h stores at L3
  if (threadIdx.x < 64) {                 // wave 0 runs the protocol
    const int lane = threadIdx.x;
    int rel = 0;
    if (lane == 0) {
      unsigned a = __hip_atomic_fetch_add(grpBase, 1u, HIP_RLX, HIP_AGT);
      if (a == 32u * tstep - 1u) rel = 1; // I am the releaser
    }
    rel = __shfl(rel, 0);
    unsigned* flags = grpBase + 128;
    if (rel) {
      if (lane < 32)
        __hip_atomic_store(flags + lane * 16, tstep, HIP_RLX, HIP_AGT);
      if (lane == 0)
        __hip_atomic_store(Pme, tstep, HIP_RLX, HIP_AGT);
    } else if (lane == 0) {
      int spins = 0;
      while (__hip_atomic_load(flags + cb * 16, HIP_RLX, HIP_AGT) < tstep) {
        __builtin_amdgcn_s_sleep(1);
        if (++spins > (1 << 24)) break;   // safety: never hang
      }
    }
    if (lane == 0) {
      if (pneed > 0) {
        int spins = 0;
        while ((int)__hip_atomic_load(Pother, HIP_RLX, HIP_AGT) < pneed) {
          __builtin_amdgcn_s_sleep(1);
          if (++spins > (1 << 24)) break;
        }
      }
      __builtin_amdgcn_fence(__ATOMIC_ACQUIRE, "agent");  // one inv per step
    }
  }
  __syncthreads();
}

// ---------------------------------------------------------------------------
// Persistent LSTM. XCD-affine decode: cls = wg&7 -> (layer = cls>>2, rb =
// cls&3); cb = wg>>3 (0..31). 512 threads = 8 waves: wave = kh*4 + ws;
// kh 0 -> k<512 (+cell epilogue), kh 1 -> k>=512 (+LDS reduce).
// h = bf16-hi, 2 units per u32: slot = 256 rows x 256 u32 (256 KB).
// h0 = 4-slot ring; h1 = 2-slot ping-pong (same gating as round 9).
// LDS: 128KB weights (fragment-linear swizzled) + 16KB reduce.
// ---------------------------------------------------------------------------
#define REDOFF 131072
#define BHU 65536       // u32 per h slot (256 rows x 256)

__global__ __launch_bounds__(512, 1) void lstm_persist(
    const unsigned* __restrict__ seqP,     // time-major [t][row][512] (lo|hi)
    unsigned* __restrict__ h0P, unsigned* __restrict__ h1P,
    const short* __restrict__ Wf, const float* __restrict__ biasF,
    const int* __restrict__ slen, unsigned* __restrict__ bar)
{
  extern __shared__ __align__(16) char bsw[];
  const int wg = blockIdx.x;
  const int cls = wg & 7;                          // XCD affinity class
  const int layer = cls >> 2;
  const int rb = cls & 3;                          // ensemble e == rb
  const int cb = wg >> 3;                          // 0..31
  const int tid = threadIdx.x;
  const int wave = tid >> 6, lane = tid & 63;
  const int kh = wave >> 2, ws = wave & 3;         // k-half, row-tile

  // ---- stage weight slice into LDS, fragment-linear swizzled ----
  const short* Wfe = Wf + ((size_t)(layer * 4 + rb) * 2048 + cb * 64) * 1024;
  #pragma unroll
  for (int i = 0; i < 16; ++i) {
    int f = (i << 9) + tid;                        // 0..8191 fragments
    int col = f >> 7, fr = f & 127;
    s16x8 v = *reinterpret_cast<const s16x8*>(Wfe + (size_t)col * 1024 + (fr << 3));
    int byo = (fr << 10) + (((col << 4)) ^ ((fr & 7) << 4));
    *reinterpret_cast<s16x8*>(bsw + byo) = v;
  }
  __syncthreads();

  const int j = lane & 15;
  const int g = lane >> 4;
  const int koff = g << 3;                         // elems
  const int rowg = rb * 64 + ws * 16 + j;          // A row for this lane
  const int rbase = rb * 64 + ws * 16 + (g << 2);  // epilogue rows (kh==0)
  const float* bp = biasF + (size_t)(layer * 4 + rb) * 2048 + cb * 64 + j;
  const float bi = bp[0], bff = bp[16], bg = bp[32], bo = bp[48];
  int msl[4];
  #pragma unroll
  for (int r = 0; r < 4; ++r) msl[r] = slen[rbase + r];

  float creg[4] = {0.f, 0.f, 0.f, 0.f};
  float hreg[4] = {0.f, 0.f, 0.f, 0.f};
  unsigned* grpBase = bar + (cls << 10);           // 4KB per group
  unsigned* Pme     = bar + 8192 + (cls << 4);
  unsigned* Pother  = bar + 8192 + ((cls ^ 4) << 4);
  const int fragbase = kh << 6;                    // kh0: 0..63, kh1: 64..127

  // initial gate: layer1 needs h0[0] (P0>=1); one fence before first loads.
  if (tid == 0) {
    if (layer == 1) {
      int spins = 0;
      while (__hip_atomic_load(Pother, HIP_RLX, HIP_AGT) < 1u) {
        __builtin_amdgcn_s_sleep(1);
        if (++spins > (1 << 24)) break;
      }
    }
    __builtin_amdgcn_fence(__ATOMIC_ACQUIRE, "agent");
  }
  __syncthreads();

  for (int t = 0; t < 256; ++t) {
    f32x4 acc[4] = {}, accL[4] = {};

    if (kh == 0 && layer == 0) {
      // ---- seq path: packed fp32 (lo|hi) u32, hi/lo 2-term MFMA ----
      const unsigned* ap = seqP + (size_t)t * 131072 + (size_t)rowg * 512 + koff;
      #pragma unroll
      for (int q = 0; q < 16; ++q) {
        uint4 r0 = *reinterpret_cast<const uint4*>(ap + (q << 5));
        uint4 r1 = *reinterpret_cast<const uint4*>(ap + (q << 5) + 4);
        s16x8 ahi, alo;
        unpack_pk(r0, r1, ahi, alo);
        const int frag = (q << 2) | g;
        const int fb_ = frag << 10;
        const int xm_ = (frag & 7) << 4;
        #pragma unroll
        for (int cf = 0; cf < 4; ++cf) {
          const int byo_ = fb_ + ((((cf << 8) | (j << 4))) ^ xm_);
          s16x8 b_ = *reinterpret_cast<const s16x8*>(bsw + byo_);
          acc[cf] = __builtin_amdgcn_mfma_f32_16x16x32_bf16(
              __builtin_bit_cast(bf16x8, ahi), __builtin_bit_cast(bf16x8, b_),
              acc[cf], 0, 0, 0);
          accL[cf] = __builtin_amdgcn_mfma_f32_16x16x32_bf16(
              __builtin_bit_cast(bf16x8, alo), __builtin_bit_cast(bf16x8, b_),
              accL[cf], 0, 0, 0);
        }
      }
    } else {
      // ---- h path: bf16-hi pair-packed, direct s16x8, 1-term MFMA ----
      const unsigned* ap;
      if (kh == 0) {        // layer1: h0 of this step
        ap = h0P + (size_t)((t + 1) & 3) * BHU + (size_t)rowg * 256 + (g << 2);
      } else {              // own layer's previous h
        ap = (layer == 0 ? h0P + (size_t)(t & 3) * BHU
                         : h1P + (size_t)(t & 1) * BHU)
           + (size_t)rowg * 256 + (g << 2);
      }
      #pragma unroll
      for (int q = 0; q < 16; ++q) {
        s16x8 a = __builtin_bit_cast(s16x8,
            *reinterpret_cast<const uint4*>(ap + (q << 4)));
        const int frag = fragbase + ((q << 2) | g);
        const int fb_ = frag << 10;
        const int xm_ = (frag & 7) << 4;
        #pragma unroll
        for (int cf = 0; cf < 4; ++cf) {
          const int byo_ = fb_ + ((((cf << 8) | (j << 4))) ^ xm_);
          s16x8 b_ = *reinterpret_cast<const s16x8*>(bsw + byo_);
          acc[cf] = __builtin_amdgcn_mfma_f32_16x16x32_bf16(
              __builtin_bit_cast(bf16x8, a), __builtin_bit_cast(bf16x8, b_),
              acc[cf], 0, 0, 0);
        }
      }
    }

    // ---- kh1: deposit partials; kh0: finish cell after sync ----
    if (kh == 1) {
      #pragma unroll
      for (int r = 0; r < 4; ++r) {
        const int lrow = ws * 16 + (g << 2) + r;
        f32x4 v = {acc[0][r], acc[1][r], acc[2][r], acc[3][r]};
        *reinterpret_cast<f32x4*>(bsw + REDOFF + lrow * 256 + j * 16) = v;
      }
    }
    __syncthreads();
    if (kh == 0) {
      unsigned* hOut = (layer == 0)
          ? h0P + (size_t)((t + 1) & 3) * BHU
          : h1P + (size_t)((t & 1) ^ 1) * BHU;
      #pragma unroll
      for (int r = 0; r < 4; ++r) {
        const int lrow = ws * 16 + (g << 2) + r;
        f32x4 red = *reinterpret_cast<const f32x4*>(bsw + REDOFF + lrow * 256 + j * 16);
        const int row = rbase + r;
        float zi = acc[0][r] + accL[0][r] + red[0] + bi;
        float zf = acc[1][r] + accL[1][r] + red[1] + bff;
        float zg = acc[2][r] + accL[2][r] + red[2] + bg;
        float zo = acc[3][r] + accL[3][r] + red[3] + bo;
        float cn = sigf(zf) * creg[r] + sigf(zi) * tanhf_fast(zg);
        float hn = sigf(zo) * tanhf_fast(cn);
        if (t >= msl[r]) { cn = creg[r]; hn = hreg[r]; }   // masked: carry
        creg[r] = cn; hreg[r] = hn;
        unsigned hu = (unsigned)(unsigned short)f2bfs(hn);
        unsigned pr = __shfl_xor(hu, 1);     // partner unit (j^1)
        if (!(lane & 1)) {                   // even j stores units (j, j+1)
          __hip_atomic_store(
              &hOut[(size_t)row * 256 + (cb << 3) + (j >> 1)],
              (pr << 16) | hu, HIP_RLX, HIP_AGT);
        }
      }
    }

    // barrier + publish P=t+1 + gate next step + fence.
    // layer0 step t+1 overwrites h0[t-2] -> needs P1 >= t-2.
    // layer1 step t+1 reads h0[t+1]      -> needs P0 >= t+2.
    int pneed = (t < 255) ? (layer == 0 ? t - 2 : t + 2) : 0;
    step_sync(grpBase, Pme, Pother, cb, (unsigned)(t + 1), pneed);
  }
}

// ---------------------------------------------------------------------------
// Head GEMM: 64x64 tile, B (bf16 hi) from global, A = bf16-hi u16 arrays,
// single-term MFMA. EPI 1 = relu6 -> u16 bf16; EPI 2 = f32 out.
// ---------------------------------------------------------------------------
template<int EPI>
__global__ __launch_bounds__(256) void head_gemm(
    const unsigned short* __restrict__ a0, int sA0,
    const unsigned short* __restrict__ a1, int sA1, int kSplit,
    const short* __restrict__ Wh, const float* __restrict__ bias,
    int N, int K,
    unsigned short* __restrict__ outH, float* __restrict__ outf)
{
  const int cb = blockIdx.x, rb = blockIdx.y;     // e == rb
  const int tid = threadIdx.x, wave = tid >> 6, lane = tid & 63;
  const int j = lane & 15;
  const int rowg = rb * 64 + wave * 16 + j;
  const int koff = (lane >> 4) << 3;
  const short* We = Wh + ((size_t)rb * N + cb * 64) * K;
  f32x4 acc[4] = {};
  for (int ks = 0; ks < (K >> 5); ++ks) {
    const int kl = (ks << 5) + koff;
    const unsigned short* ap = (kl < kSplit)
        ? (a0 + (size_t)rowg * sA0 + kl)
        : (a1 + (size_t)rowg * sA1 + (kl - kSplit));
    s16x8 a = *reinterpret_cast<const s16x8*>(ap);
    #pragma unroll
    for (int cf = 0; cf < 4; ++cf) {
      const int ccol = (cf << 4) + j;
      s16x8 b = *reinterpret_cast<const s16x8*>(We + (size_t)ccol * K + kl);
      acc[cf] = __builtin_amdgcn_mfma_f32_16x16x32_bf16(
          __builtin_bit_cast(bf16x8, a), __builtin_bit_cast(bf16x8, b),
          acc[cf], 0, 0, 0);
    }
  }
  const int rbase = rb * 64 + wave * 16 + ((lane >> 4) << 2);
  #pragma unroll
  for (int cf = 0; cf < 4; ++cf) {
    const int col = cb * 64 + cf * 16 + j;
    const float bb = bias[(size_t)rb * N + col];
    #pragma unroll
    for (int r = 0; r < 4; ++r) {
      float z = acc[cf][r] + bb;
      if (EPI == 1) {
        z = fminf(fmaxf(z, 0.f), 6.f);
        outH[(size_t)(rbase + r) * N + col] = (unsigned short)f2bfs(z);
      } else {
        outf[(size_t)(rbase + r) * N + col] = z;
      }
    }
  }
}

// ---------------------------------------------------------------------------
// Prep kernels.
// ---------------------------------------------------------------------------
__global__ __launch_bounds__(256) void fold_lstm(
    const float* __restrict__ W, const float* __restrict__ U,
    const float* __restrict__ al, const float* __restrict__ ral,
    const float* __restrict__ ga, const float* __restrict__ rga,
    short* __restrict__ Wf)
{
  __shared__ float T[64][65];
  const int tid = threadIdx.x;
  const int kb = blockIdx.x * 64;
  const int cb = blockIdx.y;
  const int le = blockIdx.z;
  const int l  = le >> 2;
  const int kl = tid >> 2;
  const int g  = tid & 3;
  const int k  = kb + kl;
  const bool isW = k < 512;
  const int kk = isW ? k : k - 512;
  const float* src = (isW ? W : U) + ((size_t)l * 512 + kk) * 2048;
  const float  a   = (isW ? al : ral)[(size_t)le * 512 + kk];
  const float* gam = (isW ? ga : rga) + (size_t)le * 2048;
  const int colBase = g * 512 + cb * 16;
  const float4* s4 = reinterpret_cast<const float4*>(src + colBase);
  const float4* g4 = reinterpret_cast<const float4*>(gam + colBase);
  #pragma unroll
  for (int q = 0; q < 4; ++q) {
    float4 v = s4[q], gv = g4[q];
    T[kl][g * 16 + q * 4 + 0] = v.x * a * gv.x;
    T[kl][g * 16 + q * 4 + 1] = v.y * a * gv.y;
    T[kl][g * 16 + q * 4 + 2] = v.z * a * gv.z;
    T[kl][g * 16 + q * 4 + 3] = v.w * a * gv.w;
  }
  __syncthreads();
  const int cl = tid >> 2, kq0 = (tid & 3) * 16;
  alignas(16) short tH[16];
  #pragma unroll
  for (int q = 0; q < 16; ++q) tH[q] = f2bfs(T[kq0 + q][cl]);
  size_t dst = ((size_t)le * 2048 + cb * 64 + cl) * 1024 + kb + kq0;
  *reinterpret_cast<s16x8*>(Wf + dst)     = *reinterpret_cast<s16x8*>(tH);
  *reinterpret_cast<s16x8*>(Wf + dst + 8) = *reinterpret_cast<s16x8*>(tH + 8);
}

__global__ __launch_bounds__(256) void fold_plain(
    const float* __restrict__ src, const float* __restrict__ al,
    const float* __restrict__ ga, short* __restrict__ dst, int N, int K)
{
  __shared__ float T[64][65];
  const int tid = threadIdx.x;
  const int kb = blockIdx.x * 64;
  const int nb = blockIdx.y;
  const int e  = blockIdx.z;
  const int kl = tid >> 2;
  const int c0 = (tid & 3) * 16;
  const int k  = kb + kl;
  const float a = al[(size_t)e * K + k];
  const int colBase = nb * 64 + c0;
  const float4* s4 = reinterpret_cast<const float4*>(src + (size_t)k * N + colBase);
  const float4* g4 = reinterpret_cast<const float4*>(ga + (size_t)e * N + colBase);
  #pragma unroll
  for (int q = 0; q < 4; ++q) {
    float4 v = s4[q], gv = g4[q];
    T[kl][c0 + q * 4 + 0] = v.x * a * gv.x;
    T[kl][c0 + q * 4 + 1] = v.y * a * gv.y;
    T[kl][c0 + q * 4 + 2] = v.z * a * gv.z;
    T[kl][c0 + q * 4 + 3] = v.w * a * gv.w;
  }
  __syncthreads();
  const int cl = tid >> 2, kq0 = (tid & 3) * 16;
  alignas(16) short tH[16];
  #pragma unroll
  for (int q = 0; q < 16; ++q) tH[q] = f2bfs(T[kq0 + q][cl]);
  size_t d = ((size_t)e * N + nb * 64 + cl) * K + kb + kq0;
  *reinterpret_cast<s16x8*>(dst + d)     = *reinterpret_cast<s16x8*>(tH);
  *reinterpret_cast<s16x8*>(dst + d + 8) = *reinterpret_cast<s16x8*>(tH + 8);
}

__global__ void fold_bias_lstm(const float* __restrict__ b, float* __restrict__ bf) {
  int idx = blockIdx.x * 256 + threadIdx.x;          // 16384
  int cp = idx & 2047, le = idx >> 11;
  int ublk = cp >> 6, g = (cp >> 4) & 3, jj = cp & 15;
  bf[idx] = b[(size_t)le * 2048 + g * 512 + ublk * 16 + jj];
}

// fp32 -> bf16-hi u16
__global__ void cvt_hi(const float* __restrict__ s,
                       unsigned short* __restrict__ d, int n) {
  int i = blockIdx.x * blockDim.x + threadIdx.x;
  if (i < n) d[i] = (unsigned short)f2bfs(s[i]);
}

// seq [row][t][512] fp32 -> packed (lo|hi) u32, TIME-MAJOR [t][row][512]
__global__ __launch_bounds__(128) void pack_seq(const float* __restrict__ s,
                                                unsigned* __restrict__ d) {
  const int t = blockIdx.x;        // 256
  const int row = blockIdx.y;      // 256
  const int d0 = threadIdx.x * 4;  // 128 threads x 4 elems
  float4 v = *reinterpret_cast<const float4*>(
      s + ((size_t)row * 256 + t) * 512 + d0);
  uint4 o; short h, l;
  split2(v.x, h, l); o.x = ((unsigned)(unsigned short)l << 16) | (unsigned)(unsigned short)h;
  split2(v.y, h, l); o.y = ((unsigned)(unsigned short)l << 16) | (unsigned)(unsigned short)h;
  split2(v.z, h, l); o.z = ((unsigned)(unsigned short)l << 16) | (unsigned)(unsigned short)h;
  split2(v.w, h, l); o.w = ((unsigned)(unsigned short)l << 16) | (unsigned)(unsigned short)h;
  *reinterpret_cast<uint4*>(d + ((size_t)t * 256 + row) * 512 + d0) = o;
}

__global__ void zero_ws(float4* p, int n) {
  int i = blockIdx.x * blockDim.x + threadIdx.x;
  if (i < n) p[i] = make_float4(0.f, 0.f, 0.f, 0.f);
}

__global__ void init_bar(unsigned* bar) {
  int i = blockIdx.x * 256 + threadIdx.x;
  if (i < 16384) bar[i] = 0u;
}

// ---------------------------------------------------------------------------
// workspace layout (bytes)
// ---------------------------------------------------------------------------
constexpr size_t OFF_WF    = 0;                      // 2*4*2048*1024*2 = 33554432
constexpr size_t OFF_WHID  = 33554432;               // 4*256*768*2     = 1572864
constexpr size_t OFF_WOUT  = OFF_WHID + 1572864;     // 4*64*256*2      = 131072
constexpr size_t OFF_BIASF = OFF_WOUT + 131072;      // 16384*4         = 65536
constexpr size_t OFF_CTXH  = OFF_BIASF + 65536;      // 65536*2         = 131072
constexpr size_t OFF_H0P   = OFF_CTXH + 131072;      // 4*256*256*4     = 1048576
constexpr size_t OFF_H1P   = OFF_H0P + 1048576;      // 2*256*256*4     = 524288
constexpr size_t OFF_HIDH  = OFF_H1P + 524288;       // 256*256*2       = 131072
constexpr size_t OFF_BAR   = OFF_HIDH + 131072;      // 65536
constexpr size_t OFF_SEQP  = OFF_BAR + 65536;        // 33554432*4 = 134217728

extern "C" void kernel_launch(void* const* d_in, const int* in_sizes, int n_in,
                              void* d_out, int out_size, void* d_ws, size_t ws_size,
                              hipStream_t stream) {
  (void)in_sizes; (void)n_in; (void)out_size; (void)ws_size;
  const float* seq  = (const float*)d_in[0];
  const float* ctx  = (const float*)d_in[1];
  const int*   slen = (const int*)d_in[2];
  const float* lW   = (const float*)d_in[3];
  const float* lU   = (const float*)d_in[4];
  const float* lb   = (const float*)d_in[5];
  const float* lal  = (const float*)d_in[6];
  const float* lga  = (const float*)d_in[7];
  const float* lral = (const float*)d_in[8];
  const float* lrga = (const float*)d_in[9];
  const float* hW   = (const float*)d_in[10];
  const float* hb   = (const float*)d_in[11];
  const float* hal  = (const float*)d_in[12];
  const float* hga  = (const float*)d_in[13];
  const float* oW   = (const float*)d_in[14];
  const float* ob   = (const float*)d_in[15];
  const float* oal  = (const float*)d_in[16];
  const float* oga  = (const float*)d_in[17];

  char* ws = (char*)d_ws;
  short*          Wf    = (short*)(ws + OFF_WF);
  short*          Whid  = (short*)(ws + OFF_WHID);
  short*          Wout  = (short*)(ws + OFF_WOUT);
  float*          biasF = (float*)(ws + OFF_BIASF);
  unsigned short* ctxH  = (unsigned short*)(ws + OFF_CTXH);
  unsigned*       h0P   = (unsigned*)(ws + OFF_H0P);
  unsigned*       h1P   = (unsigned*)(ws + OFF_H1P);
  unsigned short* hidH  = (unsigned short*)(ws + OFF_HIDH);
  unsigned*       bar   = (unsigned*)(ws + OFF_BAR);
  unsigned*       seqP  = (unsigned*)(ws + OFF_SEQP);

  // allow 144 KiB dynamic LDS
  (void)hipFuncSetAttribute(reinterpret_cast<const void*>(lstm_persist),
                            hipFuncAttributeMaxDynamicSharedMemorySize, 147456);

  // prep (every call: deterministic, no caching)
  fold_lstm<<<dim3(16, 32, 8), 256, 0, stream>>>(lW, lU, lal, lral, lga, lrga, Wf);
  fold_plain<<<dim3(12, 4, 4), 256, 0, stream>>>(hW, hal, hga, Whid, 256, 768);
  fold_plain<<<dim3(4, 1, 4), 256, 0, stream>>>(oW, oal, oga, Wout, 64, 256);
  fold_bias_lstm<<<64, 256, 0, stream>>>(lb, biasF);
  cvt_hi<<<256, 256, 0, stream>>>(ctx, ctxH, 65536);
  pack_seq<<<dim3(256, 256), 128, 0, stream>>>(seq, seqP);
  zero_ws<<<384, 256, 0, stream>>>((float4*)(ws + OFF_H0P), 1572864 / 16);
  init_bar<<<64, 256, 0, stream>>>(bar);

  // the whole recurrence in one persistent kernel (256 WGs = 1/CU, 8 waves)
  lstm_persist<<<256, 512, 147456, stream>>>(seqP, h0P, h1P, Wf, biasF, slen, bar);

  // head: hidden = relu6(((h1,ctx)*a)@hid_W*g + b); out = ((hid*a)@out_W*g + b)
  head_gemm<1><<<dim3(4, 4), 256, 0, stream>>>(
      (const unsigned short*)h1P /* final h1 in slot 0 */, 512,
      ctxH, 256, 512,
      Whid, hb, 256, 768, hidH, nullptr);
  head_gemm<2><<<dim3(1, 4), 256, 0, stream>>>(
      hidH, 256,
      hidH, 256, 256,
      Wout, ob, 64, 256,
      nullptr, (float*)d_out);
}